// Round 10
// baseline (2312.474 us; speedup 1.0000x reference)
//
#include <hip/hip_runtime.h>
#include <stdint.h>

// Problem constants
#define NB      16
#define NPTS    4096
#define CPTS    64
#define NPOINT  1024
#define NSAMPLE 32
#define NROWS   (NB*NPOINT*NSAMPLE)   // 524288 rows of (b,s,k)

// f32 -> bf16 (RNE) and bf16 -> f32 (intermediates only; in/out are f32)
__device__ __forceinline__ unsigned short f2bf(float f){
  uint32_t u = __float_as_uint(f);
  uint32_t r = u + 0x7fffu + ((u>>16)&1u);
  return (unsigned short)(r>>16);
}
__device__ __forceinline__ float bf2f(unsigned short u){ return __uint_as_float(((uint32_t)u)<<16); }
__device__ __forceinline__ float lo16(uint32_t d){ return __uint_as_float(d<<16); }
__device__ __forceinline__ float hi16(uint32_t d){ return __uint_as_float(d & 0xffff0000u); }
__device__ __forceinline__ uint32_t pack2(float a, float b){ return ((uint32_t)f2bf(b)<<16) | (uint32_t)f2bf(a); }

// u64 cross-lane max via DPP (VALU) — row_shr 1/2/4/8 then row_bcast 15/31;
// lane63 ends with the wave max.  bound_ctrl=1 gives 0 for invalid lanes;
// 0 is a safe identity (all keys > 0).  Verified correct in R8/R9 (passed).
#define DPP_PAIR(k, CTRL) \
  ( ((unsigned long long)(uint32_t)__builtin_amdgcn_update_dpp(0, (int)(uint32_t)((k)>>32), CTRL, 0xF, 0xF, true) << 32) \
    | (uint32_t)__builtin_amdgcn_update_dpp(0, (int)(uint32_t)(k), CTRL, 0xF, 0xF, true) )

// ---------------------------------------------------------------------------
// K1: Farthest point sampling.  R9 post-mortem: payload-tracking grew live
// state past the allocator's occupancy-driven VGPR cap (VGPR_Count 68->56
// with ~85 live) -> point arrays spilled to scratch (L2-resident => invisible
// in FETCH/WRITE, +380cyc/iter).  Occupancy is irrelevant (16 blocks on 256
// CUs), so: 512 threads x 8 pts/thread (array state 32 VGPR) and
// __launch_bounds__(512,1) => VGPR budget 512, no spill possible.
// Design retained from R9: best COORDS tracked in registers (constant-index
// cndmask), DPP u64 reduce, owning lane (okey==wkey, unique via ~idx) writes
// (key,x,y,z) to its wave slot, post-barrier 8-slot payload tournament.
// Key=(f32bits(d)<<32)|~idx: dist>=0 => f32 bits order-isomorphic; ~idx =
// np.argmax first-occurrence tie-break.  Selection arithmetic unchanged
// (__fsub_rn/__fmul_rn/__fadd_rn, fminf, strict >) => bit-identical indices.
// ---------------------------------------------------------------------------
__global__ __launch_bounds__(512, 1) void fps_kernel(const float* __restrict__ xyz,
                                                     float* __restrict__ newxyz_f,
                                                     float* __restrict__ out){
  __shared__ uint4 s_A[2][8];   // {keyhi, keylo, xbits, ybits} per wave
  __shared__ float s_Z[2][8];
  const int b = blockIdx.x, t = threadIdx.x;
  const float* Xb = xyz + (size_t)b*NPTS*3;
  float px[8], py[8], pz[8], dd[8];
  #pragma unroll
  for (int i=0;i<8;++i){
    int n = t*8+i;
    px[i]=Xb[n*3+0]; py[i]=Xb[n*3+1]; pz[i]=Xb[n*3+2]; dd[i]=1e10f;
  }
  float cx=Xb[0], cy=Xb[1], cz=Xb[2];   // point 0 broadcast (L1 hit)
  if (t==0){
    size_t o=(size_t)b*NPOINT*3;   // sample 0 is index 0 (scan emits prior carry)
    newxyz_f[o]=cx; newxyz_f[o+1]=cy; newxyz_f[o+2]=cz;
    out[o]=cx; out[o+1]=cy; out[o+2]=cz;
  }
  const int lane = t&63, wid = t>>6;
  for (int s=1;s<NPOINT;++s){
    float bv=-1.0f, bx=0.f, by=0.f, bz=0.f; int bi=0;
    #pragma unroll
    for (int i=0;i<8;++i){
      float dx=__fsub_rn(px[i],cx), dy=__fsub_rn(py[i],cy), dz=__fsub_rn(pz[i],cz);
      float d=__fadd_rn(__fadd_rn(__fmul_rn(dx,dx),__fmul_rn(dy,dy)),__fmul_rn(dz,dz));
      float nd=fminf(dd[i],d); dd[i]=nd;
      bool gt = nd>bv;                  // ascending i + strict > => lowest idx on tie
      bv = gt?nd:bv; bi = gt?(t*8+i):bi;
      bx = gt?px[i]:bx; by = gt?py[i]:by; bz = gt?pz[i]:bz;
    }
    const unsigned long long okey =
      ((unsigned long long)__float_as_uint(bv)<<32) | (uint32_t)(~bi);
    unsigned long long key = okey, o;
    o = DPP_PAIR(key,0x111); key = (o>key)?o:key;   // row_shr:1
    o = DPP_PAIR(key,0x112); key = (o>key)?o:key;   // row_shr:2
    o = DPP_PAIR(key,0x114); key = (o>key)?o:key;   // row_shr:4
    o = DPP_PAIR(key,0x118); key = (o>key)?o:key;   // row_shr:8
    o = DPP_PAIR(key,0x142); key = (o>key)?o:key;   // row_bcast:15
    o = DPP_PAIR(key,0x143); key = (o>key)?o:key;   // row_bcast:31
    uint32_t klo = (uint32_t)__builtin_amdgcn_readlane((int)(uint32_t)key, 63);
    uint32_t khi = (uint32_t)__builtin_amdgcn_readlane((int)(uint32_t)(key>>32), 63);
    const unsigned long long wkey = ((unsigned long long)khi<<32)|klo;
    const int buf = s&1;
    if (okey == wkey){                  // exactly one lane per wave (idx unique)
      s_A[buf][wid] = make_uint4(khi, klo, __float_as_uint(bx), __float_as_uint(by));
      s_Z[buf][wid] = bz;
    }
    __syncthreads();
    // 8-slot payload tournament (broadcast LDS reads, 3 levels)
    unsigned long long K[8]; uint32_t X[8], Y[8]; float Z[8];
    #pragma unroll
    for (int w=0;w<8;++w){
      uint4 A=s_A[buf][w];
      K[w]=((unsigned long long)A.x<<32)|A.y; X[w]=A.z; Y[w]=A.w; Z[w]=s_Z[buf][w];
    }
    #pragma unroll
    for (int st=1; st<8; st<<=1)
      #pragma unroll
      for (int w=0;w<8;w+=2*st){
        bool c = K[w+st]>K[w];
        K[w]=c?K[w+st]:K[w]; X[w]=c?X[w+st]:X[w];
        Y[w]=c?Y[w+st]:Y[w]; Z[w]=c?Z[w+st]:Z[w];
      }
    cx=__uint_as_float(X[0]); cy=__uint_as_float(Y[0]); cz=Z[0];
    if (t==0){
      size_t o2=((size_t)b*NPOINT+s)*3;
      newxyz_f[o2]=cx; newxyz_f[o2+1]=cy; newxyz_f[o2+2]=cz;
      out[o2]=cx; out[o2+1]=cy; out[o2+2]=cz;
    }
    // no 2nd barrier: next iter writes the OTHER slot buffer; reaching that
    // write requires passing this barrier, which all waves' reads precede.
  }
}

// ---------------------------------------------------------------------------
// K2: Ball query (reverted to R8's 4096-block version — R9's 256-block variant
// was ~neutral-to-worse).  One wave per center; batch xyz staged in LDS.
// First NSAMPLE in-radius indices in ascending j (== sort semantics) via
// ballot + prefix popcount; pad with first index.
// ---------------------------------------------------------------------------
__global__ __launch_bounds__(256) void ballq_kernel(const float* __restrict__ xyz,
                                                    const float* __restrict__ newxyz_f,
                                                    int* __restrict__ ballidx){
  __shared__ float s_x[NPTS], s_y[NPTS], s_z[NPTS];
  __shared__ int s_list[4][NSAMPLE];
  const int b  = blockIdx.x >> 8;     // 256 s-groups per batch
  const int sg = blockIdx.x & 255;
  const int t = threadIdx.x;
  const float* Xb = xyz + (size_t)b*NPTS*3;
  for (int n=t;n<NPTS;n+=256){
    s_x[n]=Xb[n*3+0]; s_y[n]=Xb[n*3+1]; s_z[n]=Xb[n*3+2];
  }
  __syncthreads();
  const int lane = t&63, wid = t>>6;
  const int s = sg*4 + wid;
  size_t co = ((size_t)b*NPOINT+s)*3;
  const float cx=newxyz_f[co], cy=newxyz_f[co+1], cz=newxyz_f[co+2];
  const float R2 = 0.04f;             // f32(0.2**2), NEP-50 weak-scalar promotion
  int count = 0;
  for (int j0=0; j0<NPTS && count<NSAMPLE; j0+=64){
    int j=j0+lane;
    float dx=__fsub_rn(cx,s_x[j]), dy=__fsub_rn(cy,s_y[j]), dz=__fsub_rn(cz,s_z[j]);
    float sq=__fadd_rn(__fadd_rn(__fmul_rn(dx,dx),__fmul_rn(dy,dy)),__fmul_rn(dz,dz));
    bool in = !(sq > R2);
    unsigned long long m = __ballot(in);
    int before = __popcll(m & ((1ull<<lane)-1ull));
    int pos = count + before;
    if (in && pos < NSAMPLE) s_list[wid][pos] = j;
    count += __popcll(m);
  }
  int c = count < NSAMPLE ? count : NSAMPLE;   // >=1: center is in its own ball
  int first = s_list[wid][0];
  if (lane >= c && lane < NSAMPLE) s_list[wid][lane] = first;
  if (lane < NSAMPLE) ballidx[((size_t)b*NPOINT+s)*NSAMPLE + lane] = s_list[wid][lane];
}

// ---------------------------------------------------------------------------
// K3: layer 1 — gather + concat + (67 -> 64) matmul + bias -> h (bf16).
// LDS-staged coalesced gather; 2 threads per row, acc[16] (no private arrays
// with dynamic indexing -> no scratch demotion).
// ---------------------------------------------------------------------------
#define L1_STRIDE 71
__global__ __launch_bounds__(256,3) void layer1_kernel(const float* __restrict__ xyz,
    const float* __restrict__ points, const int* __restrict__ ballidx,
    const float* __restrict__ newxyz_f, const float* __restrict__ w0,
    const float* __restrict__ b0, unsigned short* __restrict__ h){
  __shared__ float s_w[67*32];            // [c][o_local], c: 0..63=points, 64..66=xyz
  __shared__ float s_b[32];
  __shared__ float s_x[128*L1_STRIDE];    // 128 rows x 71 (67 used)
  __shared__ int   s_j[128];
  const int t = threadIdx.x;
  const int tile = blockIdx.x >> 1;       // 4096 tiles of 128 rows
  const int half = blockIdx.x & 1;        // output channels [half*32, half*32+32)
  const int tileBase = tile*128;
  for (int i=t;i<67*32;i+=256){
    int c=i>>5, oL=i&31;
    int srcc = (c<64) ? (c+3) : (c-64);
    s_w[i] = w0[(half*32+oL)*67 + srcc];
  }
  if (t<32) s_b[t]=b0[half*32+t];
  if (t<128) s_j[t]=ballidx[tileBase+t];
  __syncthreads();
  #pragma unroll
  for (int it=0; it<8; ++it){
    int r = it*16 + (t>>4);
    int row = tileBase + r;
    int bb = row >> 15;                   // 32768 rows per batch
    int j  = s_j[r];
    float4 pv = *(const float4*)(points + ((size_t)bb*NPTS + (size_t)j)*CPTS + (t&15)*4);
    float* xr = s_x + r*L1_STRIDE + (t&15)*4;
    xr[0]=pv.x; xr[1]=pv.y; xr[2]=pv.z; xr[3]=pv.w;
  }
  if (t<128){
    int row = tileBase + t;
    int bs  = row >> 5;
    int bb  = bs >> 10;
    int j   = s_j[t];
    const float* xr = xyz + ((size_t)bb*NPTS + (size_t)j)*3;
    const float* cp = newxyz_f + (size_t)bs*3;
    float* xd = s_x + t*L1_STRIDE + 64;
    xd[0]=(xr[0]-cp[0])/0.2f; xd[1]=(xr[1]-cp[1])/0.2f; xd[2]=(xr[2]-cp[2])/0.2f;
  }
  __syncthreads();
  const int r    = t & 127;
  const int osub = (t>>7)*16;
  const float* xp = s_x + r*L1_STRIDE;
  float acc[16];
  #pragma unroll
  for (int o=0;o<16;++o) acc[o]=0.0f;
  for (int c=0;c<67;++c){
    float xv = xp[c];
    const float4* wr=(const float4*)(s_w + c*32 + osub);
    #pragma unroll
    for (int q=0;q<4;++q){ float4 w=wr[q];
      acc[4*q+0]=fmaf(xv,w.x,acc[4*q+0]); acc[4*q+1]=fmaf(xv,w.y,acc[4*q+1]);
      acc[4*q+2]=fmaf(xv,w.z,acc[4*q+2]); acc[4*q+3]=fmaf(xv,w.w,acc[4*q+3]); }
  }
  uint4* od=(uint4*)(h + (size_t)(tileBase+r)*64 + half*32 + osub);
  #pragma unroll
  for (int q=0;q<2;++q){
    uint4 v;
    v.x=pack2(acc[8*q+0]+s_b[osub+8*q+0], acc[8*q+1]+s_b[osub+8*q+1]);
    v.y=pack2(acc[8*q+2]+s_b[osub+8*q+2], acc[8*q+3]+s_b[osub+8*q+3]);
    v.z=pack2(acc[8*q+4]+s_b[osub+8*q+4], acc[8*q+5]+s_b[osub+8*q+5]);
    v.w=pack2(acc[8*q+6]+s_b[osub+8*q+6], acc[8*q+7]+s_b[osub+8*q+7]);
    od[q]=v;
  }
}

// ---------------------------------------------------------------------------
// Stats over h (bf16, C=64): per-channel sum/sumsq, coalesced uint4 reads,
// LDS block-reduce, one atomicAdd pair per channel per block.
// ---------------------------------------------------------------------------
__global__ __launch_bounds__(256) void stats64_kernel(const unsigned short* __restrict__ h,
                                                      float* __restrict__ st){
  __shared__ float s_red[4][64][8], s_red2[4][64][8];
  const int t=threadIdx.x, lane=t&63, wid=t>>6;
  const int gw = blockIdx.x*4+wid;         // 512 blocks -> 0..2047 waves
  const int rsub = lane>>3;
  float sm[8], sq[8];
  #pragma unroll
  for (int j=0;j<8;++j){ sm[j]=0.f; sq[j]=0.f; }
  for (int it=0; it<32; ++it){
    size_t row = (size_t)gw*256 + it*8 + rsub;
    const uint4* p = (const uint4*)(h + row*64) + (lane&7);
    uint4 v = *p;
    uint32_t ds4[4]={v.x,v.y,v.z,v.w};
    #pragma unroll
    for (int dj=0;dj<4;++dj){
      float a=lo16(ds4[dj]), b2=hi16(ds4[dj]);
      sm[2*dj]+=a;   sq[2*dj]  =fmaf(a,a,sq[2*dj]);
      sm[2*dj+1]+=b2; sq[2*dj+1]=fmaf(b2,b2,sq[2*dj+1]);
    }
  }
  #pragma unroll
  for (int j=0;j<8;++j){ s_red[wid][lane][j]=sm[j]; s_red2[wid][lane][j]=sq[j]; }
  __syncthreads();
  if (t<64){
    float ts=0.f,tq=0.f;
    #pragma unroll
    for (int w=0;w<4;++w)
      #pragma unroll
      for (int m=0;m<8;++m){ int l=(t>>3)+8*m; ts+=s_red[w][l][t&7]; tq+=s_red2[w][l][t&7]; }
    atomicAdd(&st[t*2], ts); atomicAdd(&st[t*2+1], tq);
  }
}

// ---------------------------------------------------------------------------
// K4: layer 2 — (64 -> 64) matmul + bias, in place.  BN(stats0)+ReLU applied
// while staging 128 rows into an LDS tile (stride 65); 2 threads per row,
// acc[32] fully unrolled; no private arrays -> no scratch demotion.
// ---------------------------------------------------------------------------
__global__ __launch_bounds__(256,3) void layer2_kernel(unsigned short* __restrict__ h,
    const float* __restrict__ st, const float* __restrict__ g,
    const float* __restrict__ be, const float* __restrict__ w1,
    const float* __restrict__ b1){
  __shared__ float s_w[64*64];            // 16 KB  [c][o]
  __shared__ float s_x[128*65];           // 33.3 KB
  __shared__ float s_b[64], s_scale[64], s_shift[64];
  const int t=threadIdx.x;
  const int tileBase = blockIdx.x*128;    // 4096 blocks
  for (int i=t;i<64*64;i+=256){ int c=i>>6, o=i&63; s_w[i]=w1[o*64+c]; }
  if (t<64){
    s_b[t]=b1[t];
    float mu=st[t*2]*(1.0f/NROWS);
    float var=st[t*2+1]*(1.0f/NROWS)-mu*mu;
    float inv=1.0f/sqrtf(var+1e-5f);
    s_scale[t]=inv*g[t]; s_shift[t]=be[t]-mu*inv*g[t];
  }
  __syncthreads();
  #pragma unroll
  for (int it=0; it<4; ++it){
    int idx = it*256 + t;
    int r = idx>>3, seg = idx&7;
    uint4 v = *((const uint4*)(h + (size_t)(tileBase+r)*64) + seg);
    float* xd = s_x + r*65 + seg*8;
    uint32_t ds4[4]={v.x,v.y,v.z,v.w};
    #pragma unroll
    for (int dj=0;dj<4;++dj){
      int c = seg*8 + dj*2;
      xd[dj*2+0]=fmaxf(fmaf(lo16(ds4[dj]),s_scale[c],  s_shift[c]),  0.0f);
      xd[dj*2+1]=fmaxf(fmaf(hi16(ds4[dj]),s_scale[c+1],s_shift[c+1]),0.0f);
    }
  }
  __syncthreads();
  const int r    = t & 127;
  const int osub = (t>>7)*32;
  const float* xp = s_x + r*65;
  float acc[32];
  #pragma unroll
  for (int o=0;o<32;++o) acc[o]=0.0f;
  for (int c=0;c<64;++c){
    float xv = xp[c];
    const float4* wr=(const float4*)(s_w + c*64 + osub);
    #pragma unroll
    for (int q=0;q<8;++q){ float4 w=wr[q];
      acc[4*q+0]=fmaf(xv,w.x,acc[4*q+0]); acc[4*q+1]=fmaf(xv,w.y,acc[4*q+1]);
      acc[4*q+2]=fmaf(xv,w.z,acc[4*q+2]); acc[4*q+3]=fmaf(xv,w.w,acc[4*q+3]); }
  }
  uint4* od=(uint4*)(h + (size_t)(tileBase+r)*64 + osub);
  #pragma unroll
  for (int q=0;q<4;++q){
    uint4 v;
    v.x=pack2(acc[8*q+0]+s_b[osub+8*q+0], acc[8*q+1]+s_b[osub+8*q+1]);
    v.y=pack2(acc[8*q+2]+s_b[osub+8*q+2], acc[8*q+3]+s_b[osub+8*q+3]);
    v.z=pack2(acc[8*q+4]+s_b[osub+8*q+4], acc[8*q+5]+s_b[osub+8*q+5]);
    v.w=pack2(acc[8*q+6]+s_b[osub+8*q+6], acc[8*q+7]+s_b[osub+8*q+7]);
    od[q]=v;
  }
}

// ---------------------------------------------------------------------------
// K5: layer 3 fused — BN(stats1)+ReLU (at stage time), (64 -> 128) matmul +
// bias, per-s max/min over K=32 + BN3 partial sums.  One 32-row s-group per
// block (16384 blocks); x tile stride 65; out tile f32 stride 133; 8 threads
// per row x acc[16]; partial sums to part[] (atomic-free), reduced by K5b.
// ---------------------------------------------------------------------------
__global__ __launch_bounds__(256,3) void layer3mm_kernel(const unsigned short* __restrict__ h,
    const float* __restrict__ st, const float* __restrict__ g,
    const float* __restrict__ be, const float* __restrict__ w2,
    const float* __restrict__ b2, float* __restrict__ mm, float* __restrict__ part){
  __shared__ unsigned short s_w[64*128];  // 16 KB  s_w[c*128+o]=bf16(w2[o][c])
  __shared__ float s_x[32*65];            // 8.3 KB
  __shared__ float s_o[32*133];           // 17 KB
  __shared__ float s_scale[64], s_shift[64], s_b2[128];
  const int t=threadIdx.x;
  const int sgBase = blockIdx.x*32;       // row base of this s-group
  for (int i=t;i<64*128;i+=256){ int c=i>>7, o=i&127; s_w[i]=f2bf(w2[o*64+c]); }
  if (t<64){
    float mu=st[t*2]*(1.0f/NROWS);
    float var=st[t*2+1]*(1.0f/NROWS)-mu*mu;
    float inv=1.0f/sqrtf(var+1e-5f);
    s_scale[t]=inv*g[t]; s_shift[t]=be[t]-mu*inv*g[t];
  }
  if (t<128) s_b2[t]=b2[t];
  __syncthreads();
  {
    int r = t>>3, seg = t&7;
    uint4 v = *((const uint4*)(h + (size_t)(sgBase+r)*64) + seg);
    float* xd = s_x + r*65 + seg*8;
    uint32_t ds4[4]={v.x,v.y,v.z,v.w};
    #pragma unroll
    for (int dj=0;dj<4;++dj){
      int c = seg*8 + dj*2;
      xd[dj*2+0]=fmaxf(fmaf(lo16(ds4[dj]),s_scale[c],  s_shift[c]),  0.0f);
      xd[dj*2+1]=fmaxf(fmaf(hi16(ds4[dj]),s_scale[c+1],s_shift[c+1]),0.0f);
    }
  }
  __syncthreads();
  {
    const int r    = t & 31;
    const int osub = (t>>5)*16;
    const float* xp = s_x + r*65;
    float acc[16];
    #pragma unroll
    for (int o=0;o<16;++o) acc[o]=0.0f;
    for (int c=0;c<64;++c){
      float xv = xp[c];
      const uint4* wr=(const uint4*)(s_w + c*128 + osub);
      #pragma unroll
      for (int q=0;q<2;++q){
        uint4 wu=wr[q];
        acc[8*q+0]=fmaf(xv,lo16(wu.x),acc[8*q+0]); acc[8*q+1]=fmaf(xv,hi16(wu.x),acc[8*q+1]);
        acc[8*q+2]=fmaf(xv,lo16(wu.y),acc[8*q+2]); acc[8*q+3]=fmaf(xv,hi16(wu.y),acc[8*q+3]);
        acc[8*q+4]=fmaf(xv,lo16(wu.z),acc[8*q+4]); acc[8*q+5]=fmaf(xv,hi16(wu.z),acc[8*q+5]);
        acc[8*q+6]=fmaf(xv,lo16(wu.w),acc[8*q+6]); acc[8*q+7]=fmaf(xv,hi16(wu.w),acc[8*q+7]);
      }
    }
    float* op = s_o + r*133 + osub;
    #pragma unroll
    for (int o=0;o<16;++o) op[o] = acc[o] + s_b2[osub+o];
  }
  __syncthreads();
  if (t<128){
    float mx=-3e38f, mn=3e38f, sm=0.f, sq=0.f;
    #pragma unroll
    for (int r=0;r<32;++r){
      float v = s_o[r*133 + t];
      mx=fmaxf(mx,v); mn=fminf(mn,v); sm+=v; sq=fmaf(v,v,sq);
    }
    float* mp = mm + (size_t)blockIdx.x*256;
    mp[t]     = mx;
    mp[128+t] = mn;
    part[(size_t)blockIdx.x*256 + t]       = sm;
    part[(size_t)blockIdx.x*256 + 128 + t] = sq;
  }
}

// ---------------------------------------------------------------------------
// K5b: reduce part[16384][256] -> st2 (interleaved {sum,sumsq} per channel).
// ---------------------------------------------------------------------------
__global__ __launch_bounds__(256) void reduce_kernel(const float* __restrict__ part,
                                                     float* __restrict__ st2){
  const int t=threadIdx.x;
  const int base = blockIdx.x*64;
  float acc=0.f;
  for (int r=0;r<64;++r) acc += part[(size_t)(base+r)*256 + t];
  if (t<128) atomicAdd(&st2[t*2], acc);
  else       atomicAdd(&st2[(t-128)*2+1], acc);
}

// ---------------------------------------------------------------------------
// K6: BN(stats2) on max (or min if scale<0) + ReLU -> new_points (f32).
// ---------------------------------------------------------------------------
__global__ __launch_bounds__(256) void final_kernel(const float* __restrict__ mm,
    const float* __restrict__ st, const float* __restrict__ g,
    const float* __restrict__ be, float* __restrict__ out){
  __shared__ float s_scale[128], s_shift[128];
  const int t=threadIdx.x;
  if (t<128){
    float mu=st[t*2]*(1.0f/NROWS);
    float var=st[t*2+1]*(1.0f/NROWS)-mu*mu;
    float inv=1.0f/sqrtf(var+1e-5f);
    s_scale[t]=inv*g[t]; s_shift[t]=be[t]-mu*inv*g[t];
  }
  __syncthreads();
  const int idx = blockIdx.x*256+t;       // bs*128 + ch
  const int ch = idx & 127, bs = idx >> 7;
  float sc=s_scale[ch];
  float v = (sc>=0.f)? mm[(size_t)bs*256+ch] : mm[(size_t)bs*256+128+ch];
  out[(size_t)NB*NPOINT*3 + idx] = fmaxf(fmaf(v,sc,s_shift[ch]),0.0f);
}

// ---------------------------------------------------------------------------
extern "C" void kernel_launch(void* const* d_in, const int* in_sizes, int n_in,
                              void* d_out, int out_size, void* d_ws, size_t ws_size,
                              hipStream_t stream) {
  const float* xyz    = (const float*)d_in[0];
  const float* points = (const float*)d_in[1];
  const float* w0 = (const float*)d_in[2];
  const float* b0 = (const float*)d_in[3];
  const float* g0 = (const float*)d_in[4];
  const float* be0= (const float*)d_in[5];
  const float* w1 = (const float*)d_in[6];
  const float* b1 = (const float*)d_in[7];
  const float* g1 = (const float*)d_in[8];
  const float* be1= (const float*)d_in[9];
  const float* w2 = (const float*)d_in[10];
  const float* b2 = (const float*)d_in[11];
  const float* g2 = (const float*)d_in[12];
  const float* be2= (const float*)d_in[13];
  float* out = (float*)d_out;             // f32 output per reference dtype
  char* ws = (char*)d_ws;

  // ws layout (100 MiB total):
  //   [0,        196608)    newxyz_f (16,1024,3) f32
  //   [196608,   2293760)   ballidx  (16,1024,32) i32
  //   [2293760,  2296832)   stats: 3 slots x 256 f32 {sum,sumsq interleaved}
  //   [4 MiB,    20 MiB)    mm: (16384, {max,min}, 128) f32
  //   [20 MiB,   84 MiB)    h: (524288, 64) bf16 — h1, then h2 in place
  //   [84 MiB,   100 MiB)   part: (16384, 256) f32 BN3 partial sums
  float* newxyz_f = (float*)(ws);
  int*   ballidx  = (int*)(ws + 196608);
  float* stats    = (float*)(ws + 2293760);
  float* mm       = (float*)(ws + 4194304);
  unsigned short* h = (unsigned short*)(ws + 20971520);
  float* part     = (float*)(ws + 88080384);

  hipMemsetAsync(stats, 0, 3072, stream);
  hipLaunchKernelGGL(fps_kernel,     dim3(NB),    dim3(512), 0, stream, xyz, newxyz_f, out);
  hipLaunchKernelGGL(ballq_kernel,   dim3(4096),  dim3(256), 0, stream, xyz, newxyz_f, ballidx);
  hipLaunchKernelGGL(layer1_kernel,  dim3(8192),  dim3(256), 0, stream,
                     xyz, points, ballidx, newxyz_f, w0, b0, h);
  hipLaunchKernelGGL(stats64_kernel, dim3(512),   dim3(256), 0, stream, h, stats + 0);
  hipLaunchKernelGGL(layer2_kernel,  dim3(4096),  dim3(256), 0, stream,
                     h, stats + 0, g0, be0, w1, b1);
  hipLaunchKernelGGL(stats64_kernel, dim3(512),   dim3(256), 0, stream, h, stats + 256);
  hipLaunchKernelGGL(layer3mm_kernel,dim3(16384), dim3(256), 0, stream,
                     h, stats + 256, g1, be1, w2, b2, mm, part);
  hipLaunchKernelGGL(reduce_kernel,  dim3(256),   dim3(256), 0, stream, part, stats + 512);
  hipLaunchKernelGGL(final_kernel,   dim3(8192),  dim3(256), 0, stream,
                     mm, stats + 512, g2, be2, out);
}

// Round 11
// 1396.544 us; speedup vs baseline: 1.6559x; 1.6559x over previous
//
#include <hip/hip_runtime.h>
#include <stdint.h>

// Problem constants
#define NB      16
#define NPTS    4096
#define CPTS    64
#define NPOINT  1024
#define NSAMPLE 32
#define NROWS   (NB*NPOINT*NSAMPLE)   // 524288 rows of (b,s,k)

// f32 -> bf16 (RNE) and bf16 -> f32 (intermediates only; in/out are f32)
__device__ __forceinline__ unsigned short f2bf(float f){
  uint32_t u = __float_as_uint(f);
  uint32_t r = u + 0x7fffu + ((u>>16)&1u);
  return (unsigned short)(r>>16);
}
__device__ __forceinline__ float bf2f(unsigned short u){ return __uint_as_float(((uint32_t)u)<<16); }
__device__ __forceinline__ float lo16(uint32_t d){ return __uint_as_float(d<<16); }
__device__ __forceinline__ float hi16(uint32_t d){ return __uint_as_float(d & 0xffff0000u); }
__device__ __forceinline__ uint32_t pack2(float a, float b){ return ((uint32_t)f2bf(b)<<16) | (uint32_t)f2bf(a); }

// u64 cross-lane max via DPP (VALU) — bound_ctrl=1 gives 0 for invalid lanes;
// 0 is a safe identity (all keys > 0).  Verified correct in R8/R9/R10 (passed).
#define DPP_PAIR(k, CTRL) \
  ( ((unsigned long long)(uint32_t)__builtin_amdgcn_update_dpp(0, (int)(uint32_t)((k)>>32), CTRL, 0xF, 0xF, true) << 32) \
    | (uint32_t)__builtin_amdgcn_update_dpp(0, (int)(uint32_t)(k), CTRL, 0xF, 0xF, true) )

// ---------------------------------------------------------------------------
// K1: Farthest point sampling.  R9/R10 post-mortem: payload-in-registers
// designs blow the allocator's occupancy-driven VGPR cap (~48-56) and spill
// the per-iteration-hot point arrays to scratch (invisible in FETCH/WRITE —
// L2-resident — but +1-2k cyc/iter).  LESSON: fps must need <= ~56 VGPRs.
// This is R8's verified design (coords in LDS, gather by index, no payload
// regs) with two register-neutral latency cuts:
//   - 512 thr x 8 pts/lane: point arrays 32 VGPRs, distance-update VALU
//     time halves vs R8's 256x16.
//   - final cross-wave reduce: each lane reads slot lane&7, 3 DPP max steps
//     (row_shr 1/2/4 -> lane7 = max of slots 0..7), readlane(7) — replaces
//     R8's serial 4-key chain (~60cyc vs ~160), only 4 extra live VGPRs.
// Key=(f32bits(d)<<32)|~idx: dist>=0 => f32 bits order-isomorphic; ~idx =
// np.argmax first-occurrence tie-break.  Selection arithmetic unchanged
// (__fsub_rn/__fmul_rn/__fadd_rn, fminf, strict >) => bit-identical indices.
// ---------------------------------------------------------------------------
__global__ __launch_bounds__(512) void fps_kernel(const float* __restrict__ xyz,
                                                  float* __restrict__ newxyz_f,
                                                  float* __restrict__ out){
  __shared__ float s_x[NPTS], s_y[NPTS], s_z[NPTS];
  __shared__ unsigned long long s_k[2][8];
  const int b = blockIdx.x, t = threadIdx.x;
  const float* Xb = xyz + (size_t)b*NPTS*3;
  float px[8], py[8], pz[8], dd[8];
  #pragma unroll
  for (int i=0;i<8;++i){
    int n = t*8+i;
    float x = Xb[n*3+0], y = Xb[n*3+1], z = Xb[n*3+2];
    px[i]=x; py[i]=y; pz[i]=z; dd[i]=1e10f;
    s_x[n]=x; s_y[n]=y; s_z[n]=z;
  }
  if (t==0){
    size_t o=(size_t)b*NPOINT*3;   // sample 0 is index 0 (scan emits prior carry)
    newxyz_f[o]=px[0]; newxyz_f[o+1]=py[0]; newxyz_f[o+2]=pz[0];
    out[o]=px[0]; out[o+1]=py[0]; out[o+2]=pz[0];
  }
  __syncthreads();
  float cx=s_x[0], cy=s_y[0], cz=s_z[0];
  const int lane = t&63;
  const int wid  = t>>6;
  for (int s=1;s<NPOINT;++s){
    float bv=-1.0f; int bi=0;
    #pragma unroll
    for (int i=0;i<8;++i){
      float dx=__fsub_rn(px[i],cx), dy=__fsub_rn(py[i],cy), dz=__fsub_rn(pz[i],cz);
      float d=__fadd_rn(__fadd_rn(__fmul_rn(dx,dx),__fmul_rn(dy,dy)),__fmul_rn(dz,dz));
      float nd=fminf(dd[i],d); dd[i]=nd;
      if (nd>bv){ bv=nd; bi=t*8+i; }    // ascending i + strict > => lowest idx on tie
    }
    unsigned long long key =
      ((unsigned long long)__float_as_uint(bv)<<32) | (uint32_t)(~bi);
    unsigned long long o;
    o = DPP_PAIR(key,0x111); key = (o>key)?o:key;   // row_shr:1
    o = DPP_PAIR(key,0x112); key = (o>key)?o:key;   // row_shr:2
    o = DPP_PAIR(key,0x114); key = (o>key)?o:key;   // row_shr:4
    o = DPP_PAIR(key,0x118); key = (o>key)?o:key;   // row_shr:8
    o = DPP_PAIR(key,0x142); key = (o>key)?o:key;   // row_bcast:15
    o = DPP_PAIR(key,0x143); key = (o>key)?o:key;   // row_bcast:31
    uint32_t klo = (uint32_t)__builtin_amdgcn_readlane((int)(uint32_t)key, 63);
    uint32_t khi = (uint32_t)__builtin_amdgcn_readlane((int)(uint32_t)(key>>32), 63);
    const int buf = s&1;
    if (lane==0) s_k[buf][wid] = ((unsigned long long)khi<<32)|klo;
    __syncthreads();
    // second-level reduce: every 8-lane group holds all 8 wave slots
    unsigned long long k = s_k[buf][lane&7];
    o = DPP_PAIR(k,0x111); k = (o>k)?o:k;           // row_shr:1
    o = DPP_PAIR(k,0x112); k = (o>k)?o:k;           // row_shr:2
    o = DPP_PAIR(k,0x114); k = (o>k)?o:k;           // row_shr:4  -> lane7 = max
    uint32_t flo = (uint32_t)__builtin_amdgcn_readlane((int)(uint32_t)k, 7);
    int fi = (int)(~flo);
    cx=s_x[fi]; cy=s_y[fi]; cz=s_z[fi];
    if (t==0){
      size_t o2=((size_t)b*NPOINT+s)*3;
      newxyz_f[o2]=cx; newxyz_f[o2+1]=cy; newxyz_f[o2+2]=cz;
      out[o2]=cx; out[o2+1]=cy; out[o2+2]=cz;
    }
    // no 2nd barrier: iter s+2 rewrites this buffer only after the barrier
    // of iter s+1, which all of iter s's reads precede.
  }
}

// ---------------------------------------------------------------------------
// K2: Ball query (R8's 4096-block version).  One wave per center; batch xyz
// staged in LDS.  First NSAMPLE in-radius indices in ascending j (== sort
// semantics) via ballot + prefix popcount; pad with first index.
// ---------------------------------------------------------------------------
__global__ __launch_bounds__(256) void ballq_kernel(const float* __restrict__ xyz,
                                                    const float* __restrict__ newxyz_f,
                                                    int* __restrict__ ballidx){
  __shared__ float s_x[NPTS], s_y[NPTS], s_z[NPTS];
  __shared__ int s_list[4][NSAMPLE];
  const int b  = blockIdx.x >> 8;     // 256 s-groups per batch
  const int sg = blockIdx.x & 255;
  const int t = threadIdx.x;
  const float* Xb = xyz + (size_t)b*NPTS*3;
  for (int n=t;n<NPTS;n+=256){
    s_x[n]=Xb[n*3+0]; s_y[n]=Xb[n*3+1]; s_z[n]=Xb[n*3+2];
  }
  __syncthreads();
  const int lane = t&63, wid = t>>6;
  const int s = sg*4 + wid;
  size_t co = ((size_t)b*NPOINT+s)*3;
  const float cx=newxyz_f[co], cy=newxyz_f[co+1], cz=newxyz_f[co+2];
  const float R2 = 0.04f;             // f32(0.2**2), NEP-50 weak-scalar promotion
  int count = 0;
  for (int j0=0; j0<NPTS && count<NSAMPLE; j0+=64){
    int j=j0+lane;
    float dx=__fsub_rn(cx,s_x[j]), dy=__fsub_rn(cy,s_y[j]), dz=__fsub_rn(cz,s_z[j]);
    float sq=__fadd_rn(__fadd_rn(__fmul_rn(dx,dx),__fmul_rn(dy,dy)),__fmul_rn(dz,dz));
    bool in = !(sq > R2);
    unsigned long long m = __ballot(in);
    int before = __popcll(m & ((1ull<<lane)-1ull));
    int pos = count + before;
    if (in && pos < NSAMPLE) s_list[wid][pos] = j;
    count += __popcll(m);
  }
  int c = count < NSAMPLE ? count : NSAMPLE;   // >=1: center is in its own ball
  int first = s_list[wid][0];
  if (lane >= c && lane < NSAMPLE) s_list[wid][lane] = first;
  if (lane < NSAMPLE) ballidx[((size_t)b*NPOINT+s)*NSAMPLE + lane] = s_list[wid][lane];
}

// ---------------------------------------------------------------------------
// K3: layer 1 — gather + concat + (67 -> 64) matmul + bias -> h (bf16).
// LDS-staged coalesced gather; 2 threads per row, acc[16] (no private arrays
// with dynamic indexing -> no scratch demotion).
// ---------------------------------------------------------------------------
#define L1_STRIDE 71
__global__ __launch_bounds__(256,3) void layer1_kernel(const float* __restrict__ xyz,
    const float* __restrict__ points, const int* __restrict__ ballidx,
    const float* __restrict__ newxyz_f, const float* __restrict__ w0,
    const float* __restrict__ b0, unsigned short* __restrict__ h){
  __shared__ float s_w[67*32];            // [c][o_local], c: 0..63=points, 64..66=xyz
  __shared__ float s_b[32];
  __shared__ float s_x[128*L1_STRIDE];    // 128 rows x 71 (67 used)
  __shared__ int   s_j[128];
  const int t = threadIdx.x;
  const int tile = blockIdx.x >> 1;       // 4096 tiles of 128 rows
  const int half = blockIdx.x & 1;        // output channels [half*32, half*32+32)
  const int tileBase = tile*128;
  for (int i=t;i<67*32;i+=256){
    int c=i>>5, oL=i&31;
    int srcc = (c<64) ? (c+3) : (c-64);
    s_w[i] = w0[(half*32+oL)*67 + srcc];
  }
  if (t<32) s_b[t]=b0[half*32+t];
  if (t<128) s_j[t]=ballidx[tileBase+t];
  __syncthreads();
  #pragma unroll
  for (int it=0; it<8; ++it){
    int r = it*16 + (t>>4);
    int row = tileBase + r;
    int bb = row >> 15;                   // 32768 rows per batch
    int j  = s_j[r];
    float4 pv = *(const float4*)(points + ((size_t)bb*NPTS + (size_t)j)*CPTS + (t&15)*4);
    float* xr = s_x + r*L1_STRIDE + (t&15)*4;
    xr[0]=pv.x; xr[1]=pv.y; xr[2]=pv.z; xr[3]=pv.w;
  }
  if (t<128){
    int row = tileBase + t;
    int bs  = row >> 5;
    int bb  = bs >> 10;
    int j   = s_j[t];
    const float* xr = xyz + ((size_t)bb*NPTS + (size_t)j)*3;
    const float* cp = newxyz_f + (size_t)bs*3;
    float* xd = s_x + t*L1_STRIDE + 64;
    xd[0]=(xr[0]-cp[0])/0.2f; xd[1]=(xr[1]-cp[1])/0.2f; xd[2]=(xr[2]-cp[2])/0.2f;
  }
  __syncthreads();
  const int r    = t & 127;
  const int osub = (t>>7)*16;
  const float* xp = s_x + r*L1_STRIDE;
  float acc[16];
  #pragma unroll
  for (int o=0;o<16;++o) acc[o]=0.0f;
  for (int c=0;c<67;++c){
    float xv = xp[c];
    const float4* wr=(const float4*)(s_w + c*32 + osub);
    #pragma unroll
    for (int q=0;q<4;++q){ float4 w=wr[q];
      acc[4*q+0]=fmaf(xv,w.x,acc[4*q+0]); acc[4*q+1]=fmaf(xv,w.y,acc[4*q+1]);
      acc[4*q+2]=fmaf(xv,w.z,acc[4*q+2]); acc[4*q+3]=fmaf(xv,w.w,acc[4*q+3]); }
  }
  uint4* od=(uint4*)(h + (size_t)(tileBase+r)*64 + half*32 + osub);
  #pragma unroll
  for (int q=0;q<2;++q){
    uint4 v;
    v.x=pack2(acc[8*q+0]+s_b[osub+8*q+0], acc[8*q+1]+s_b[osub+8*q+1]);
    v.y=pack2(acc[8*q+2]+s_b[osub+8*q+2], acc[8*q+3]+s_b[osub+8*q+3]);
    v.z=pack2(acc[8*q+4]+s_b[osub+8*q+4], acc[8*q+5]+s_b[osub+8*q+5]);
    v.w=pack2(acc[8*q+6]+s_b[osub+8*q+6], acc[8*q+7]+s_b[osub+8*q+7]);
    od[q]=v;
  }
}

// ---------------------------------------------------------------------------
// Stats over h (bf16, C=64): per-channel sum/sumsq, coalesced uint4 reads,
// LDS block-reduce, one atomicAdd pair per channel per block.
// ---------------------------------------------------------------------------
__global__ __launch_bounds__(256) void stats64_kernel(const unsigned short* __restrict__ h,
                                                      float* __restrict__ st){
  __shared__ float s_red[4][64][8], s_red2[4][64][8];
  const int t=threadIdx.x, lane=t&63, wid=t>>6;
  const int gw = blockIdx.x*4+wid;         // 512 blocks -> 0..2047 waves
  const int rsub = lane>>3;
  float sm[8], sq[8];
  #pragma unroll
  for (int j=0;j<8;++j){ sm[j]=0.f; sq[j]=0.f; }
  for (int it=0; it<32; ++it){
    size_t row = (size_t)gw*256 + it*8 + rsub;
    const uint4* p = (const uint4*)(h + row*64) + (lane&7);
    uint4 v = *p;
    uint32_t ds4[4]={v.x,v.y,v.z,v.w};
    #pragma unroll
    for (int dj=0;dj<4;++dj){
      float a=lo16(ds4[dj]), b2=hi16(ds4[dj]);
      sm[2*dj]+=a;   sq[2*dj]  =fmaf(a,a,sq[2*dj]);
      sm[2*dj+1]+=b2; sq[2*dj+1]=fmaf(b2,b2,sq[2*dj+1]);
    }
  }
  #pragma unroll
  for (int j=0;j<8;++j){ s_red[wid][lane][j]=sm[j]; s_red2[wid][lane][j]=sq[j]; }
  __syncthreads();
  if (t<64){
    float ts=0.f,tq=0.f;
    #pragma unroll
    for (int w=0;w<4;++w)
      #pragma unroll
      for (int m=0;m<8;++m){ int l=(t>>3)+8*m; ts+=s_red[w][l][t&7]; tq+=s_red2[w][l][t&7]; }
    atomicAdd(&st[t*2], ts); atomicAdd(&st[t*2+1], tq);
  }
}

// ---------------------------------------------------------------------------
// K4: layer 2 — (64 -> 64) matmul + bias, in place.  BN(stats0)+ReLU applied
// while staging 128 rows into an LDS tile (stride 65); 2 threads per row,
// acc[32] fully unrolled; no private arrays -> no scratch demotion.
// ---------------------------------------------------------------------------
__global__ __launch_bounds__(256,3) void layer2_kernel(unsigned short* __restrict__ h,
    const float* __restrict__ st, const float* __restrict__ g,
    const float* __restrict__ be, const float* __restrict__ w1,
    const float* __restrict__ b1){
  __shared__ float s_w[64*64];            // 16 KB  [c][o]
  __shared__ float s_x[128*65];           // 33.3 KB
  __shared__ float s_b[64], s_scale[64], s_shift[64];
  const int t=threadIdx.x;
  const int tileBase = blockIdx.x*128;    // 4096 blocks
  for (int i=t;i<64*64;i+=256){ int c=i>>6, o=i&63; s_w[i]=w1[o*64+c]; }
  if (t<64){
    s_b[t]=b1[t];
    float mu=st[t*2]*(1.0f/NROWS);
    float var=st[t*2+1]*(1.0f/NROWS)-mu*mu;
    float inv=1.0f/sqrtf(var+1e-5f);
    s_scale[t]=inv*g[t]; s_shift[t]=be[t]-mu*inv*g[t];
  }
  __syncthreads();
  #pragma unroll
  for (int it=0; it<4; ++it){
    int idx = it*256 + t;
    int r = idx>>3, seg = idx&7;
    uint4 v = *((const uint4*)(h + (size_t)(tileBase+r)*64) + seg);
    float* xd = s_x + r*65 + seg*8;
    uint32_t ds4[4]={v.x,v.y,v.z,v.w};
    #pragma unroll
    for (int dj=0;dj<4;++dj){
      int c = seg*8 + dj*2;
      xd[dj*2+0]=fmaxf(fmaf(lo16(ds4[dj]),s_scale[c],  s_shift[c]),  0.0f);
      xd[dj*2+1]=fmaxf(fmaf(hi16(ds4[dj]),s_scale[c+1],s_shift[c+1]),0.0f);
    }
  }
  __syncthreads();
  const int r    = t & 127;
  const int osub = (t>>7)*32;
  const float* xp = s_x + r*65;
  float acc[32];
  #pragma unroll
  for (int o=0;o<32;++o) acc[o]=0.0f;
  for (int c=0;c<64;++c){
    float xv = xp[c];
    const float4* wr=(const float4*)(s_w + c*64 + osub);
    #pragma unroll
    for (int q=0;q<8;++q){ float4 w=wr[q];
      acc[4*q+0]=fmaf(xv,w.x,acc[4*q+0]); acc[4*q+1]=fmaf(xv,w.y,acc[4*q+1]);
      acc[4*q+2]=fmaf(xv,w.z,acc[4*q+2]); acc[4*q+3]=fmaf(xv,w.w,acc[4*q+3]); }
  }
  uint4* od=(uint4*)(h + (size_t)(tileBase+r)*64 + osub);
  #pragma unroll
  for (int q=0;q<4;++q){
    uint4 v;
    v.x=pack2(acc[8*q+0]+s_b[osub+8*q+0], acc[8*q+1]+s_b[osub+8*q+1]);
    v.y=pack2(acc[8*q+2]+s_b[osub+8*q+2], acc[8*q+3]+s_b[osub+8*q+3]);
    v.z=pack2(acc[8*q+4]+s_b[osub+8*q+4], acc[8*q+5]+s_b[osub+8*q+5]);
    v.w=pack2(acc[8*q+6]+s_b[osub+8*q+6], acc[8*q+7]+s_b[osub+8*q+7]);
    od[q]=v;
  }
}

// ---------------------------------------------------------------------------
// K5: layer 3 fused — BN(stats1)+ReLU (at stage time), (64 -> 128) matmul +
// bias, per-s max/min over K=32 + BN3 partial sums.  One 32-row s-group per
// block (16384 blocks); x tile stride 65; out tile f32 stride 133; 8 threads
// per row x acc[16]; partial sums to part[] (atomic-free), reduced by K5b.
// ---------------------------------------------------------------------------
__global__ __launch_bounds__(256,3) void layer3mm_kernel(const unsigned short* __restrict__ h,
    const float* __restrict__ st, const float* __restrict__ g,
    const float* __restrict__ be, const float* __restrict__ w2,
    const float* __restrict__ b2, float* __restrict__ mm, float* __restrict__ part){
  __shared__ unsigned short s_w[64*128];  // 16 KB  s_w[c*128+o]=bf16(w2[o][c])
  __shared__ float s_x[32*65];            // 8.3 KB
  __shared__ float s_o[32*133];           // 17 KB
  __shared__ float s_scale[64], s_shift[64], s_b2[128];
  const int t=threadIdx.x;
  const int sgBase = blockIdx.x*32;       // row base of this s-group
  for (int i=t;i<64*128;i+=256){ int c=i>>7, o=i&127; s_w[i]=f2bf(w2[o*64+c]); }
  if (t<64){
    float mu=st[t*2]*(1.0f/NROWS);
    float var=st[t*2+1]*(1.0f/NROWS)-mu*mu;
    float inv=1.0f/sqrtf(var+1e-5f);
    s_scale[t]=inv*g[t]; s_shift[t]=be[t]-mu*inv*g[t];
  }
  if (t<128) s_b2[t]=b2[t];
  __syncthreads();
  {
    int r = t>>3, seg = t&7;
    uint4 v = *((const uint4*)(h + (size_t)(sgBase+r)*64) + seg);
    float* xd = s_x + r*65 + seg*8;
    uint32_t ds4[4]={v.x,v.y,v.z,v.w};
    #pragma unroll
    for (int dj=0;dj<4;++dj){
      int c = seg*8 + dj*2;
      xd[dj*2+0]=fmaxf(fmaf(lo16(ds4[dj]),s_scale[c],  s_shift[c]),  0.0f);
      xd[dj*2+1]=fmaxf(fmaf(hi16(ds4[dj]),s_scale[c+1],s_shift[c+1]),0.0f);
    }
  }
  __syncthreads();
  {
    const int r    = t & 31;
    const int osub = (t>>5)*16;
    const float* xp = s_x + r*65;
    float acc[16];
    #pragma unroll
    for (int o=0;o<16;++o) acc[o]=0.0f;
    for (int c=0;c<64;++c){
      float xv = xp[c];
      const uint4* wr=(const uint4*)(s_w + c*128 + osub);
      #pragma unroll
      for (int q=0;q<2;++q){
        uint4 wu=wr[q];
        acc[8*q+0]=fmaf(xv,lo16(wu.x),acc[8*q+0]); acc[8*q+1]=fmaf(xv,hi16(wu.x),acc[8*q+1]);
        acc[8*q+2]=fmaf(xv,lo16(wu.y),acc[8*q+2]); acc[8*q+3]=fmaf(xv,hi16(wu.y),acc[8*q+3]);
        acc[8*q+4]=fmaf(xv,lo16(wu.z),acc[8*q+4]); acc[8*q+5]=fmaf(xv,hi16(wu.z),acc[8*q+5]);
        acc[8*q+6]=fmaf(xv,lo16(wu.w),acc[8*q+6]); acc[8*q+7]=fmaf(xv,hi16(wu.w),acc[8*q+7]);
      }
    }
    float* op = s_o + r*133 + osub;
    #pragma unroll
    for (int o=0;o<16;++o) op[o] = acc[o] + s_b2[osub+o];
  }
  __syncthreads();
  if (t<128){
    float mx=-3e38f, mn=3e38f, sm=0.f, sq=0.f;
    #pragma unroll
    for (int r=0;r<32;++r){
      float v = s_o[r*133 + t];
      mx=fmaxf(mx,v); mn=fminf(mn,v); sm+=v; sq=fmaf(v,v,sq);
    }
    float* mp = mm + (size_t)blockIdx.x*256;
    mp[t]     = mx;
    mp[128+t] = mn;
    part[(size_t)blockIdx.x*256 + t]       = sm;
    part[(size_t)blockIdx.x*256 + 128 + t] = sq;
  }
}

// ---------------------------------------------------------------------------
// K5b: reduce part[16384][256] -> st2 (interleaved {sum,sumsq} per channel).
// ---------------------------------------------------------------------------
__global__ __launch_bounds__(256) void reduce_kernel(const float* __restrict__ part,
                                                     float* __restrict__ st2){
  const int t=threadIdx.x;
  const int base = blockIdx.x*64;
  float acc=0.f;
  for (int r=0;r<64;++r) acc += part[(size_t)(base+r)*256 + t];
  if (t<128) atomicAdd(&st2[t*2], acc);
  else       atomicAdd(&st2[(t-128)*2+1], acc);
}

// ---------------------------------------------------------------------------
// K6: BN(stats2) on max (or min if scale<0) + ReLU -> new_points (f32).
// ---------------------------------------------------------------------------
__global__ __launch_bounds__(256) void final_kernel(const float* __restrict__ mm,
    const float* __restrict__ st, const float* __restrict__ g,
    const float* __restrict__ be, float* __restrict__ out){
  __shared__ float s_scale[128], s_shift[128];
  const int t=threadIdx.x;
  if (t<128){
    float mu=st[t*2]*(1.0f/NROWS);
    float var=st[t*2+1]*(1.0f/NROWS)-mu*mu;
    float inv=1.0f/sqrtf(var+1e-5f);
    s_scale[t]=inv*g[t]; s_shift[t]=be[t]-mu*inv*g[t];
  }
  __syncthreads();
  const int idx = blockIdx.x*256+t;       // bs*128 + ch
  const int ch = idx & 127, bs = idx >> 7;
  float sc=s_scale[ch];
  float v = (sc>=0.f)? mm[(size_t)bs*256+ch] : mm[(size_t)bs*256+128+ch];
  out[(size_t)NB*NPOINT*3 + idx] = fmaxf(fmaf(v,sc,s_shift[ch]),0.0f);
}

// ---------------------------------------------------------------------------
extern "C" void kernel_launch(void* const* d_in, const int* in_sizes, int n_in,
                              void* d_out, int out_size, void* d_ws, size_t ws_size,
                              hipStream_t stream) {
  const float* xyz    = (const float*)d_in[0];
  const float* points = (const float*)d_in[1];
  const float* w0 = (const float*)d_in[2];
  const float* b0 = (const float*)d_in[3];
  const float* g0 = (const float*)d_in[4];
  const float* be0= (const float*)d_in[5];
  const float* w1 = (const float*)d_in[6];
  const float* b1 = (const float*)d_in[7];
  const float* g1 = (const float*)d_in[8];
  const float* be1= (const float*)d_in[9];
  const float* w2 = (const float*)d_in[10];
  const float* b2 = (const float*)d_in[11];
  const float* g2 = (const float*)d_in[12];
  const float* be2= (const float*)d_in[13];
  float* out = (float*)d_out;             // f32 output per reference dtype
  char* ws = (char*)d_ws;

  // ws layout (100 MiB total):
  //   [0,        196608)    newxyz_f (16,1024,3) f32
  //   [196608,   2293760)   ballidx  (16,1024,32) i32
  //   [2293760,  2296832)   stats: 3 slots x 256 f32 {sum,sumsq interleaved}
  //   [4 MiB,    20 MiB)    mm: (16384, {max,min}, 128) f32
  //   [20 MiB,   84 MiB)    h: (524288, 64) bf16 — h1, then h2 in place
  //   [84 MiB,   100 MiB)   part: (16384, 256) f32 BN3 partial sums
  float* newxyz_f = (float*)(ws);
  int*   ballidx  = (int*)(ws + 196608);
  float* stats    = (float*)(ws + 2293760);
  float* mm       = (float*)(ws + 4194304);
  unsigned short* h = (unsigned short*)(ws + 20971520);
  float* part     = (float*)(ws + 88080384);

  hipMemsetAsync(stats, 0, 3072, stream);
  hipLaunchKernelGGL(fps_kernel,     dim3(NB),    dim3(512), 0, stream, xyz, newxyz_f, out);
  hipLaunchKernelGGL(ballq_kernel,   dim3(4096),  dim3(256), 0, stream, xyz, newxyz_f, ballidx);
  hipLaunchKernelGGL(layer1_kernel,  dim3(8192),  dim3(256), 0, stream,
                     xyz, points, ballidx, newxyz_f, w0, b0, h);
  hipLaunchKernelGGL(stats64_kernel, dim3(512),   dim3(256), 0, stream, h, stats + 0);
  hipLaunchKernelGGL(layer2_kernel,  dim3(4096),  dim3(256), 0, stream,
                     h, stats + 0, g0, be0, w1, b1);
  hipLaunchKernelGGL(stats64_kernel, dim3(512),   dim3(256), 0, stream, h, stats + 256);
  hipLaunchKernelGGL(layer3mm_kernel,dim3(16384), dim3(256), 0, stream,
                     h, stats + 256, g1, be1, w2, b2, mm, part);
  hipLaunchKernelGGL(reduce_kernel,  dim3(256),   dim3(256), 0, stream, part, stats + 512);
  hipLaunchKernelGGL(final_kernel,   dim3(8192),  dim3(256), 0, stream,
                     mm, stats + 512, g2, be2, out);
}

// Round 12
// 1315.268 us; speedup vs baseline: 1.7582x; 1.0618x over previous
//
#include <hip/hip_runtime.h>
#include <stdint.h>

// Problem constants
#define NB      16
#define NPTS    4096
#define CPTS    64
#define NPOINT  1024
#define NSAMPLE 32
#define NROWS   (NB*NPOINT*NSAMPLE)   // 524288 rows of (b,s,k)

// f32 -> bf16 (RNE) and bf16 -> f32 (intermediates only; in/out are f32)
__device__ __forceinline__ unsigned short f2bf(float f){
  uint32_t u = __float_as_uint(f);
  uint32_t r = u + 0x7fffu + ((u>>16)&1u);
  return (unsigned short)(r>>16);
}
__device__ __forceinline__ float bf2f(unsigned short u){ return __uint_as_float(((uint32_t)u)<<16); }
__device__ __forceinline__ float lo16(uint32_t d){ return __uint_as_float(d<<16); }
__device__ __forceinline__ float hi16(uint32_t d){ return __uint_as_float(d & 0xffff0000u); }
__device__ __forceinline__ uint32_t pack2(float a, float b){ return ((uint32_t)f2bf(b)<<16) | (uint32_t)f2bf(a); }

// f32 max over DPP (bound_ctrl=1 -> 0 identity; distances >= 0 so safe)
#define FMAX_DPP(m, CTRL) { \
  float _o = __uint_as_float((uint32_t)__builtin_amdgcn_update_dpp(0, (int)__float_as_uint(m), CTRL, 0xF, 0xF, true)); \
  m = fmaxf(m, _o); }

// ---------------------------------------------------------------------------
// K1: Farthest point sampling.  R11 post-mortem: 512-thr (8-wave) variant was
// SLOWER than R8's 256-thr (685 vs 610us) — barrier skew + 2nd-level reduce
// outweigh halved VALU.  4 waves is the sweet spot.  This is R8's verified
// structure (coords in LDS, gather by index, ~68 VGPR — no spill) with a
// cheaper wave argmax: f32-only DPP max (6 x v_max_f32, 1-2 insts/step vs 5
// for the old u64 chain) + readlane(63) + ballot(bv==wm) + lowest-set-lane +
// readlane(bi,l).  Tie-break exact: per-lane index ranges [16L,16L+16) are
// disjoint & ordered, per-lane bi is its lowest tied index (strict >,
// ascending i) => lowest tied lane == np.argmax first occurrence.
// Cross-wave: R8's packed-u64 4-slot tournament (wave ranges ordered too).
// Selection arithmetic unchanged => bit-identical indices vs R3-R11.
// ---------------------------------------------------------------------------
__global__ __launch_bounds__(256) void fps_kernel(const float* __restrict__ xyz,
                                                  float* __restrict__ newxyz_f,
                                                  float* __restrict__ out){
  __shared__ float s_x[NPTS], s_y[NPTS], s_z[NPTS];
  __shared__ unsigned long long s_k[2][4];
  const int b = blockIdx.x, t = threadIdx.x;
  const float* Xb = xyz + (size_t)b*NPTS*3;
  float px[16], py[16], pz[16], dd[16];
  #pragma unroll
  for (int i=0;i<16;++i){
    int n = t*16+i;
    float x = Xb[n*3+0], y = Xb[n*3+1], z = Xb[n*3+2];
    px[i]=x; py[i]=y; pz[i]=z; dd[i]=1e10f;
    s_x[n]=x; s_y[n]=y; s_z[n]=z;
  }
  if (t==0){
    size_t o=(size_t)b*NPOINT*3;   // sample 0 is index 0 (scan emits prior carry)
    newxyz_f[o]=px[0]; newxyz_f[o+1]=py[0]; newxyz_f[o+2]=pz[0];
    out[o]=px[0]; out[o+1]=py[0]; out[o+2]=pz[0];
  }
  __syncthreads();
  float cx=s_x[0], cy=s_y[0], cz=s_z[0];
  const int lane = t&63, wid = t>>6;
  for (int s=1;s<NPOINT;++s){
    float bv=-1.0f; int bi=0;
    #pragma unroll
    for (int i=0;i<16;++i){
      float dx=__fsub_rn(px[i],cx), dy=__fsub_rn(py[i],cy), dz=__fsub_rn(pz[i],cz);
      float d=__fadd_rn(__fadd_rn(__fmul_rn(dx,dx),__fmul_rn(dy,dy)),__fmul_rn(dz,dz));
      float nd=fminf(dd[i],d); dd[i]=nd;
      if (nd>bv){ bv=nd; bi=t*16+i; }   // ascending i + strict > => lowest idx on tie
    }
    // wave max of distance (f32 DPP), then argmax via ballot
    float m = bv;
    FMAX_DPP(m,0x111)   // row_shr:1
    FMAX_DPP(m,0x112)   // row_shr:2
    FMAX_DPP(m,0x114)   // row_shr:4
    FMAX_DPP(m,0x118)   // row_shr:8
    FMAX_DPP(m,0x142)   // row_bcast:15
    FMAX_DPP(m,0x143)   // row_bcast:31
    float wm = __uint_as_float((uint32_t)__builtin_amdgcn_readlane((int)__float_as_uint(m), 63));
    unsigned long long mask = __ballot(bv==wm);
    int l = (int)__ffsll((unsigned long long)mask) - 1;   // lowest tied lane
    int widx = __builtin_amdgcn_readlane(bi, l);
    const int buf = s&1;
    if (lane==0)
      s_k[buf][wid] = ((unsigned long long)__float_as_uint(wm)<<32) | (uint32_t)(~widx);
    __syncthreads();
    unsigned long long k0=s_k[buf][0], k1=s_k[buf][1], k2=s_k[buf][2], k3=s_k[buf][3];
    unsigned long long ka=(k0>k1)?k0:k1, kb=(k2>k3)?k2:k3;
    unsigned long long kf=(ka>kb)?ka:kb;
    int fi = (int)(~(uint32_t)(kf & 0xffffffffu));
    cx=s_x[fi]; cy=s_y[fi]; cz=s_z[fi];
    if (t==0){
      size_t o2=((size_t)b*NPOINT+s)*3;
      newxyz_f[o2]=cx; newxyz_f[o2+1]=cy; newxyz_f[o2+2]=cz;
      out[o2]=cx; out[o2+1]=cy; out[o2+2]=cz;
    }
    // no 2nd barrier: next iter writes the OTHER slot buffer; reaching that
    // write requires passing this barrier, which all waves' reads precede.
  }
}

// ---------------------------------------------------------------------------
// K2: Ball query.  R11 post-mortem: old stage loop s_x[n]=Xb[n*3] was
// stride-768B per lane — one 64B line per element, ~3GB of L2 traffic over
// 4096 blocks.  Now: coalesced float4 AoS stage (12 ld + 12 ds_write_b128
// per thread), scan reads s_p[3j+c] (stride-3 dwords = exact 2-way bank
// aliasing, free).  Ballot + prefix-popcount core and distance
// bit-arithmetic unchanged => identical indices.
// ---------------------------------------------------------------------------
__global__ __launch_bounds__(256) void ballq_kernel(const float* __restrict__ xyz,
                                                    const float* __restrict__ newxyz_f,
                                                    int* __restrict__ ballidx){
  __shared__ float s_p[NPTS*3];       // 48 KB AoS
  __shared__ int s_list[4][NSAMPLE];
  const int b  = blockIdx.x >> 8;     // 256 s-groups per batch
  const int sg = blockIdx.x & 255;
  const int t = threadIdx.x;
  const float* Xb = xyz + (size_t)b*NPTS*3;
  {
    const float4* X4 = (const float4*)Xb;
    float4* S4 = (float4*)s_p;
    #pragma unroll
    for (int i=0;i<12;++i) S4[t + i*256] = X4[t + i*256];   // 3072 float4
  }
  __syncthreads();
  const int lane = t&63, wid = t>>6;
  const int s = sg*4 + wid;
  size_t co = ((size_t)b*NPOINT+s)*3;
  const float cx=newxyz_f[co], cy=newxyz_f[co+1], cz=newxyz_f[co+2];
  const float R2 = 0.04f;             // f32(0.2**2), NEP-50 weak-scalar promotion
  int count = 0;
  for (int j0=0; j0<NPTS && count<NSAMPLE; j0+=64){
    int j=j0+lane;
    float dx=__fsub_rn(cx,s_p[3*j]), dy=__fsub_rn(cy,s_p[3*j+1]), dz=__fsub_rn(cz,s_p[3*j+2]);
    float sq=__fadd_rn(__fadd_rn(__fmul_rn(dx,dx),__fmul_rn(dy,dy)),__fmul_rn(dz,dz));
    bool in = !(sq > R2);
    unsigned long long m = __ballot(in);
    int before = __popcll(m & ((1ull<<lane)-1ull));
    int pos = count + before;
    if (in && pos < NSAMPLE) s_list[wid][pos] = j;
    count += __popcll(m);
  }
  int c = count < NSAMPLE ? count : NSAMPLE;   // >=1: center is in its own ball
  int first = s_list[wid][0];
  if (lane >= c && lane < NSAMPLE) s_list[wid][lane] = first;
  if (lane < NSAMPLE) ballidx[((size_t)b*NPOINT+s)*NSAMPLE + lane] = s_list[wid][lane];
}

// ---------------------------------------------------------------------------
// K3: layer 1 — gather + concat + (67 -> 64) matmul + bias -> h (bf16).
// LDS-staged coalesced gather; 2 threads per row, acc[16] (no private arrays
// with dynamic indexing -> no scratch demotion).
// ---------------------------------------------------------------------------
#define L1_STRIDE 71
__global__ __launch_bounds__(256,3) void layer1_kernel(const float* __restrict__ xyz,
    const float* __restrict__ points, const int* __restrict__ ballidx,
    const float* __restrict__ newxyz_f, const float* __restrict__ w0,
    const float* __restrict__ b0, unsigned short* __restrict__ h){
  __shared__ float s_w[67*32];            // [c][o_local], c: 0..63=points, 64..66=xyz
  __shared__ float s_b[32];
  __shared__ float s_x[128*L1_STRIDE];    // 128 rows x 71 (67 used)
  __shared__ int   s_j[128];
  const int t = threadIdx.x;
  const int tile = blockIdx.x >> 1;       // 4096 tiles of 128 rows
  const int half = blockIdx.x & 1;        // output channels [half*32, half*32+32)
  const int tileBase = tile*128;
  for (int i=t;i<67*32;i+=256){
    int c=i>>5, oL=i&31;
    int srcc = (c<64) ? (c+3) : (c-64);
    s_w[i] = w0[(half*32+oL)*67 + srcc];
  }
  if (t<32) s_b[t]=b0[half*32+t];
  if (t<128) s_j[t]=ballidx[tileBase+t];
  __syncthreads();
  #pragma unroll
  for (int it=0; it<8; ++it){
    int r = it*16 + (t>>4);
    int row = tileBase + r;
    int bb = row >> 15;                   // 32768 rows per batch
    int j  = s_j[r];
    float4 pv = *(const float4*)(points + ((size_t)bb*NPTS + (size_t)j)*CPTS + (t&15)*4);
    float* xr = s_x + r*L1_STRIDE + (t&15)*4;
    xr[0]=pv.x; xr[1]=pv.y; xr[2]=pv.z; xr[3]=pv.w;
  }
  if (t<128){
    int row = tileBase + t;
    int bs  = row >> 5;
    int bb  = bs >> 10;
    int j   = s_j[t];
    const float* xr = xyz + ((size_t)bb*NPTS + (size_t)j)*3;
    const float* cp = newxyz_f + (size_t)bs*3;
    float* xd = s_x + t*L1_STRIDE + 64;
    xd[0]=(xr[0]-cp[0])/0.2f; xd[1]=(xr[1]-cp[1])/0.2f; xd[2]=(xr[2]-cp[2])/0.2f;
  }
  __syncthreads();
  const int r    = t & 127;
  const int osub = (t>>7)*16;
  const float* xp = s_x + r*L1_STRIDE;
  float acc[16];
  #pragma unroll
  for (int o=0;o<16;++o) acc[o]=0.0f;
  for (int c=0;c<67;++c){
    float xv = xp[c];
    const float4* wr=(const float4*)(s_w + c*32 + osub);
    #pragma unroll
    for (int q=0;q<4;++q){ float4 w=wr[q];
      acc[4*q+0]=fmaf(xv,w.x,acc[4*q+0]); acc[4*q+1]=fmaf(xv,w.y,acc[4*q+1]);
      acc[4*q+2]=fmaf(xv,w.z,acc[4*q+2]); acc[4*q+3]=fmaf(xv,w.w,acc[4*q+3]); }
  }
  uint4* od=(uint4*)(h + (size_t)(tileBase+r)*64 + half*32 + osub);
  #pragma unroll
  for (int q=0;q<2;++q){
    uint4 v;
    v.x=pack2(acc[8*q+0]+s_b[osub+8*q+0], acc[8*q+1]+s_b[osub+8*q+1]);
    v.y=pack2(acc[8*q+2]+s_b[osub+8*q+2], acc[8*q+3]+s_b[osub+8*q+3]);
    v.z=pack2(acc[8*q+4]+s_b[osub+8*q+4], acc[8*q+5]+s_b[osub+8*q+5]);
    v.w=pack2(acc[8*q+6]+s_b[osub+8*q+6], acc[8*q+7]+s_b[osub+8*q+7]);
    od[q]=v;
  }
}

// ---------------------------------------------------------------------------
// Stats over h (bf16, C=64): per-channel sum/sumsq, coalesced uint4 reads,
// LDS block-reduce, one atomicAdd pair per channel per block.
// ---------------------------------------------------------------------------
__global__ __launch_bounds__(256) void stats64_kernel(const unsigned short* __restrict__ h,
                                                      float* __restrict__ st){
  __shared__ float s_red[4][64][8], s_red2[4][64][8];
  const int t=threadIdx.x, lane=t&63, wid=t>>6;
  const int gw = blockIdx.x*4+wid;         // 512 blocks -> 0..2047 waves
  const int rsub = lane>>3;
  float sm[8], sq[8];
  #pragma unroll
  for (int j=0;j<8;++j){ sm[j]=0.f; sq[j]=0.f; }
  for (int it=0; it<32; ++it){
    size_t row = (size_t)gw*256 + it*8 + rsub;
    const uint4* p = (const uint4*)(h + row*64) + (lane&7);
    uint4 v = *p;
    uint32_t ds4[4]={v.x,v.y,v.z,v.w};
    #pragma unroll
    for (int dj=0;dj<4;++dj){
      float a=lo16(ds4[dj]), b2=hi16(ds4[dj]);
      sm[2*dj]+=a;   sq[2*dj]  =fmaf(a,a,sq[2*dj]);
      sm[2*dj+1]+=b2; sq[2*dj+1]=fmaf(b2,b2,sq[2*dj+1]);
    }
  }
  #pragma unroll
  for (int j=0;j<8;++j){ s_red[wid][lane][j]=sm[j]; s_red2[wid][lane][j]=sq[j]; }
  __syncthreads();
  if (t<64){
    float ts=0.f,tq=0.f;
    #pragma unroll
    for (int w=0;w<4;++w)
      #pragma unroll
      for (int m=0;m<8;++m){ int l=(t>>3)+8*m; ts+=s_red[w][l][t&7]; tq+=s_red2[w][l][t&7]; }
    atomicAdd(&st[t*2], ts); atomicAdd(&st[t*2+1], tq);
  }
}

// ---------------------------------------------------------------------------
// K4: layer 2 — (64 -> 64) matmul + bias, in place.  BN(stats0)+ReLU applied
// while staging 128 rows into an LDS tile (stride 65); 2 threads per row,
// acc[32] fully unrolled; no private arrays -> no scratch demotion.
// ---------------------------------------------------------------------------
__global__ __launch_bounds__(256,3) void layer2_kernel(unsigned short* __restrict__ h,
    const float* __restrict__ st, const float* __restrict__ g,
    const float* __restrict__ be, const float* __restrict__ w1,
    const float* __restrict__ b1){
  __shared__ float s_w[64*64];            // 16 KB  [c][o]
  __shared__ float s_x[128*65];           // 33.3 KB
  __shared__ float s_b[64], s_scale[64], s_shift[64];
  const int t=threadIdx.x;
  const int tileBase = blockIdx.x*128;    // 4096 blocks
  for (int i=t;i<64*64;i+=256){ int c=i>>6, o=i&63; s_w[i]=w1[o*64+c]; }
  if (t<64){
    s_b[t]=b1[t];
    float mu=st[t*2]*(1.0f/NROWS);
    float var=st[t*2+1]*(1.0f/NROWS)-mu*mu;
    float inv=1.0f/sqrtf(var+1e-5f);
    s_scale[t]=inv*g[t]; s_shift[t]=be[t]-mu*inv*g[t];
  }
  __syncthreads();
  #pragma unroll
  for (int it=0; it<4; ++it){
    int idx = it*256 + t;
    int r = idx>>3, seg = idx&7;
    uint4 v = *((const uint4*)(h + (size_t)(tileBase+r)*64) + seg);
    float* xd = s_x + r*65 + seg*8;
    uint32_t ds4[4]={v.x,v.y,v.z,v.w};
    #pragma unroll
    for (int dj=0;dj<4;++dj){
      int c = seg*8 + dj*2;
      xd[dj*2+0]=fmaxf(fmaf(lo16(ds4[dj]),s_scale[c],  s_shift[c]),  0.0f);
      xd[dj*2+1]=fmaxf(fmaf(hi16(ds4[dj]),s_scale[c+1],s_shift[c+1]),0.0f);
    }
  }
  __syncthreads();
  const int r    = t & 127;
  const int osub = (t>>7)*32;
  const float* xp = s_x + r*65;
  float acc[32];
  #pragma unroll
  for (int o=0;o<32;++o) acc[o]=0.0f;
  for (int c=0;c<64;++c){
    float xv = xp[c];
    const float4* wr=(const float4*)(s_w + c*64 + osub);
    #pragma unroll
    for (int q=0;q<8;++q){ float4 w=wr[q];
      acc[4*q+0]=fmaf(xv,w.x,acc[4*q+0]); acc[4*q+1]=fmaf(xv,w.y,acc[4*q+1]);
      acc[4*q+2]=fmaf(xv,w.z,acc[4*q+2]); acc[4*q+3]=fmaf(xv,w.w,acc[4*q+3]); }
  }
  uint4* od=(uint4*)(h + (size_t)(tileBase+r)*64 + osub);
  #pragma unroll
  for (int q=0;q<4;++q){
    uint4 v;
    v.x=pack2(acc[8*q+0]+s_b[osub+8*q+0], acc[8*q+1]+s_b[osub+8*q+1]);
    v.y=pack2(acc[8*q+2]+s_b[osub+8*q+2], acc[8*q+3]+s_b[osub+8*q+3]);
    v.z=pack2(acc[8*q+4]+s_b[osub+8*q+4], acc[8*q+5]+s_b[osub+8*q+5]);
    v.w=pack2(acc[8*q+6]+s_b[osub+8*q+6], acc[8*q+7]+s_b[osub+8*q+7]);
    od[q]=v;
  }
}

// ---------------------------------------------------------------------------
// K5: layer 3 fused — BN(stats1)+ReLU (at stage time), (64 -> 128) matmul +
// bias, per-s max/min over K=32 + BN3 partial sums.  One 32-row s-group per
// block (16384 blocks); x tile stride 65; out tile f32 stride 133; 8 threads
// per row x acc[16]; partial sums to part[] (atomic-free), reduced by K5b.
// ---------------------------------------------------------------------------
__global__ __launch_bounds__(256,3) void layer3mm_kernel(const unsigned short* __restrict__ h,
    const float* __restrict__ st, const float* __restrict__ g,
    const float* __restrict__ be, const float* __restrict__ w2,
    const float* __restrict__ b2, float* __restrict__ mm, float* __restrict__ part){
  __shared__ unsigned short s_w[64*128];  // 16 KB  s_w[c*128+o]=bf16(w2[o][c])
  __shared__ float s_x[32*65];            // 8.3 KB
  __shared__ float s_o[32*133];           // 17 KB
  __shared__ float s_scale[64], s_shift[64], s_b2[128];
  const int t=threadIdx.x;
  const int sgBase = blockIdx.x*32;       // row base of this s-group
  for (int i=t;i<64*128;i+=256){ int c=i>>7, o=i&127; s_w[i]=f2bf(w2[o*64+c]); }
  if (t<64){
    float mu=st[t*2]*(1.0f/NROWS);
    float var=st[t*2+1]*(1.0f/NROWS)-mu*mu;
    float inv=1.0f/sqrtf(var+1e-5f);
    s_scale[t]=inv*g[t]; s_shift[t]=be[t]-mu*inv*g[t];
  }
  if (t<128) s_b2[t]=b2[t];
  __syncthreads();
  {
    int r = t>>3, seg = t&7;
    uint4 v = *((const uint4*)(h + (size_t)(sgBase+r)*64) + seg);
    float* xd = s_x + r*65 + seg*8;
    uint32_t ds4[4]={v.x,v.y,v.z,v.w};
    #pragma unroll
    for (int dj=0;dj<4;++dj){
      int c = seg*8 + dj*2;
      xd[dj*2+0]=fmaxf(fmaf(lo16(ds4[dj]),s_scale[c],  s_shift[c]),  0.0f);
      xd[dj*2+1]=fmaxf(fmaf(hi16(ds4[dj]),s_scale[c+1],s_shift[c+1]),0.0f);
    }
  }
  __syncthreads();
  {
    const int r    = t & 31;
    const int osub = (t>>5)*16;
    const float* xp = s_x + r*65;
    float acc[16];
    #pragma unroll
    for (int o=0;o<16;++o) acc[o]=0.0f;
    for (int c=0;c<64;++c){
      float xv = xp[c];
      const uint4* wr=(const uint4*)(s_w + c*128 + osub);
      #pragma unroll
      for (int q=0;q<2;++q){
        uint4 wu=wr[q];
        acc[8*q+0]=fmaf(xv,lo16(wu.x),acc[8*q+0]); acc[8*q+1]=fmaf(xv,hi16(wu.x),acc[8*q+1]);
        acc[8*q+2]=fmaf(xv,lo16(wu.y),acc[8*q+2]); acc[8*q+3]=fmaf(xv,hi16(wu.y),acc[8*q+3]);
        acc[8*q+4]=fmaf(xv,lo16(wu.z),acc[8*q+4]); acc[8*q+5]=fmaf(xv,hi16(wu.z),acc[8*q+5]);
        acc[8*q+6]=fmaf(xv,lo16(wu.w),acc[8*q+6]); acc[8*q+7]=fmaf(xv,hi16(wu.w),acc[8*q+7]);
      }
    }
    float* op = s_o + r*133 + osub;
    #pragma unroll
    for (int o=0;o<16;++o) op[o] = acc[o] + s_b2[osub+o];
  }
  __syncthreads();
  if (t<128){
    float mx=-3e38f, mn=3e38f, sm=0.f, sq=0.f;
    #pragma unroll
    for (int r=0;r<32;++r){
      float v = s_o[r*133 + t];
      mx=fmaxf(mx,v); mn=fminf(mn,v); sm+=v; sq=fmaf(v,v,sq);
    }
    float* mp = mm + (size_t)blockIdx.x*256;
    mp[t]     = mx;
    mp[128+t] = mn;
    part[(size_t)blockIdx.x*256 + t]       = sm;
    part[(size_t)blockIdx.x*256 + 128 + t] = sq;
  }
}

// ---------------------------------------------------------------------------
// K5b: reduce part[16384][256] -> st2 (interleaved {sum,sumsq} per channel).
// ---------------------------------------------------------------------------
__global__ __launch_bounds__(256) void reduce_kernel(const float* __restrict__ part,
                                                     float* __restrict__ st2){
  const int t=threadIdx.x;
  const int base = blockIdx.x*64;
  float acc=0.f;
  for (int r=0;r<64;++r) acc += part[(size_t)(base+r)*256 + t];
  if (t<128) atomicAdd(&st2[t*2], acc);
  else       atomicAdd(&st2[(t-128)*2+1], acc);
}

// ---------------------------------------------------------------------------
// K6: BN(stats2) on max (or min if scale<0) + ReLU -> new_points (f32).
// ---------------------------------------------------------------------------
__global__ __launch_bounds__(256) void final_kernel(const float* __restrict__ mm,
    const float* __restrict__ st, const float* __restrict__ g,
    const float* __restrict__ be, float* __restrict__ out){
  __shared__ float s_scale[128], s_shift[128];
  const int t=threadIdx.x;
  if (t<128){
    float mu=st[t*2]*(1.0f/NROWS);
    float var=st[t*2+1]*(1.0f/NROWS)-mu*mu;
    float inv=1.0f/sqrtf(var+1e-5f);
    s_scale[t]=inv*g[t]; s_shift[t]=be[t]-mu*inv*g[t];
  }
  __syncthreads();
  const int idx = blockIdx.x*256+t;       // bs*128 + ch
  const int ch = idx & 127, bs = idx >> 7;
  float sc=s_scale[ch];
  float v = (sc>=0.f)? mm[(size_t)bs*256+ch] : mm[(size_t)bs*256+128+ch];
  out[(size_t)NB*NPOINT*3 + idx] = fmaxf(fmaf(v,sc,s_shift[ch]),0.0f);
}

// ---------------------------------------------------------------------------
extern "C" void kernel_launch(void* const* d_in, const int* in_sizes, int n_in,
                              void* d_out, int out_size, void* d_ws, size_t ws_size,
                              hipStream_t stream) {
  const float* xyz    = (const float*)d_in[0];
  const float* points = (const float*)d_in[1];
  const float* w0 = (const float*)d_in[2];
  const float* b0 = (const float*)d_in[3];
  const float* g0 = (const float*)d_in[4];
  const float* be0= (const float*)d_in[5];
  const float* w1 = (const float*)d_in[6];
  const float* b1 = (const float*)d_in[7];
  const float* g1 = (const float*)d_in[8];
  const float* be1= (const float*)d_in[9];
  const float* w2 = (const float*)d_in[10];
  const float* b2 = (const float*)d_in[11];
  const float* g2 = (const float*)d_in[12];
  const float* be2= (const float*)d_in[13];
  float* out = (float*)d_out;             // f32 output per reference dtype
  char* ws = (char*)d_ws;

  // ws layout (100 MiB total):
  //   [0,        196608)    newxyz_f (16,1024,3) f32
  //   [196608,   2293760)   ballidx  (16,1024,32) i32
  //   [2293760,  2296832)   stats: 3 slots x 256 f32 {sum,sumsq interleaved}
  //   [4 MiB,    20 MiB)    mm: (16384, {max,min}, 128) f32
  //   [20 MiB,   84 MiB)    h: (524288, 64) bf16 — h1, then h2 in place
  //   [84 MiB,   100 MiB)   part: (16384, 256) f32 BN3 partial sums
  float* newxyz_f = (float*)(ws);
  int*   ballidx  = (int*)(ws + 196608);
  float* stats    = (float*)(ws + 2293760);
  float* mm       = (float*)(ws + 4194304);
  unsigned short* h = (unsigned short*)(ws + 20971520);
  float* part     = (float*)(ws + 88080384);

  hipMemsetAsync(stats, 0, 3072, stream);
  hipLaunchKernelGGL(fps_kernel,     dim3(NB),    dim3(256), 0, stream, xyz, newxyz_f, out);
  hipLaunchKernelGGL(ballq_kernel,   dim3(4096),  dim3(256), 0, stream, xyz, newxyz_f, ballidx);
  hipLaunchKernelGGL(layer1_kernel,  dim3(8192),  dim3(256), 0, stream,
                     xyz, points, ballidx, newxyz_f, w0, b0, h);
  hipLaunchKernelGGL(stats64_kernel, dim3(512),   dim3(256), 0, stream, h, stats + 0);
  hipLaunchKernelGGL(layer2_kernel,  dim3(4096),  dim3(256), 0, stream,
                     h, stats + 0, g0, be0, w1, b1);
  hipLaunchKernelGGL(stats64_kernel, dim3(512),   dim3(256), 0, stream, h, stats + 256);
  hipLaunchKernelGGL(layer3mm_kernel,dim3(16384), dim3(256), 0, stream,
                     h, stats + 256, g1, be1, w2, b2, mm, part);
  hipLaunchKernelGGL(reduce_kernel,  dim3(256),   dim3(256), 0, stream, part, stats + 512);
  hipLaunchKernelGGL(final_kernel,   dim3(8192),  dim3(256), 0, stream,
                     mm, stats + 512, g2, be2, out);
}

// Round 13
// 1075.166 us; speedup vs baseline: 2.1508x; 1.2233x over previous
//
#include <hip/hip_runtime.h>
#include <stdint.h>

// Problem constants
#define NB      16
#define NPTS    4096
#define CPTS    64
#define NPOINT  1024
#define NSAMPLE 32
#define NROWS   (NB*NPOINT*NSAMPLE)   // 524288 rows of (b,s,k)

// f32 -> bf16 (RNE) and bf16 -> f32 (intermediates only; in/out are f32)
__device__ __forceinline__ unsigned short f2bf(float f){
  uint32_t u = __float_as_uint(f);
  uint32_t r = u + 0x7fffu + ((u>>16)&1u);
  return (unsigned short)(r>>16);
}
__device__ __forceinline__ float bf2f(unsigned short u){ return __uint_as_float(((uint32_t)u)<<16); }
__device__ __forceinline__ float lo16(uint32_t d){ return __uint_as_float(d<<16); }
__device__ __forceinline__ float hi16(uint32_t d){ return __uint_as_float(d & 0xffff0000u); }
__device__ __forceinline__ uint32_t pack2(float a, float b){ return ((uint32_t)f2bf(b)<<16) | (uint32_t)f2bf(a); }

// f32 max over DPP (bound_ctrl=1 -> 0 identity; distances >= 0 so safe)
#define FMAX_DPP(m, CTRL) { \
  float _o = __uint_as_float((uint32_t)__builtin_amdgcn_update_dpp(0, (int)__float_as_uint(m), CTRL, 0xF, 0xF, true)); \
  m = fmaxf(m, _o); }

typedef __attribute__((ext_vector_type(8))) short bf16x8;
typedef __attribute__((ext_vector_type(4))) float f32x4;

// ---------------------------------------------------------------------------
// K1: Farthest point sampling (R12 verified, 599us).  R8 structure (coords in
// LDS, gather by index, ~68 VGPR — no spill) + f32-only DPP wave max +
// ballot argmax.  Tie-break exact: per-lane index ranges [16L,16L+16) are
// disjoint & ordered, per-lane bi is its lowest tied index (strict >,
// ascending i) => lowest tied lane == np.argmax first occurrence.
// Cross-wave: packed-u64 4-slot tournament (wave ranges ordered too).
// ---------------------------------------------------------------------------
__global__ __launch_bounds__(256) void fps_kernel(const float* __restrict__ xyz,
                                                  float* __restrict__ newxyz_f,
                                                  float* __restrict__ out){
  __shared__ float s_x[NPTS], s_y[NPTS], s_z[NPTS];
  __shared__ unsigned long long s_k[2][4];
  const int b = blockIdx.x, t = threadIdx.x;
  const float* Xb = xyz + (size_t)b*NPTS*3;
  float px[16], py[16], pz[16], dd[16];
  #pragma unroll
  for (int i=0;i<16;++i){
    int n = t*16+i;
    float x = Xb[n*3+0], y = Xb[n*3+1], z = Xb[n*3+2];
    px[i]=x; py[i]=y; pz[i]=z; dd[i]=1e10f;
    s_x[n]=x; s_y[n]=y; s_z[n]=z;
  }
  if (t==0){
    size_t o=(size_t)b*NPOINT*3;   // sample 0 is index 0 (scan emits prior carry)
    newxyz_f[o]=px[0]; newxyz_f[o+1]=py[0]; newxyz_f[o+2]=pz[0];
    out[o]=px[0]; out[o+1]=py[0]; out[o+2]=pz[0];
  }
  __syncthreads();
  float cx=s_x[0], cy=s_y[0], cz=s_z[0];
  const int lane = t&63, wid = t>>6;
  for (int s=1;s<NPOINT;++s){
    float bv=-1.0f; int bi=0;
    #pragma unroll
    for (int i=0;i<16;++i){
      float dx=__fsub_rn(px[i],cx), dy=__fsub_rn(py[i],cy), dz=__fsub_rn(pz[i],cz);
      float d=__fadd_rn(__fadd_rn(__fmul_rn(dx,dx),__fmul_rn(dy,dy)),__fmul_rn(dz,dz));
      float nd=fminf(dd[i],d); dd[i]=nd;
      if (nd>bv){ bv=nd; bi=t*16+i; }   // ascending i + strict > => lowest idx on tie
    }
    float m = bv;
    FMAX_DPP(m,0x111)   // row_shr:1
    FMAX_DPP(m,0x112)   // row_shr:2
    FMAX_DPP(m,0x114)   // row_shr:4
    FMAX_DPP(m,0x118)   // row_shr:8
    FMAX_DPP(m,0x142)   // row_bcast:15
    FMAX_DPP(m,0x143)   // row_bcast:31
    float wm = __uint_as_float((uint32_t)__builtin_amdgcn_readlane((int)__float_as_uint(m), 63));
    unsigned long long mask = __ballot(bv==wm);
    int l = (int)__ffsll((unsigned long long)mask) - 1;   // lowest tied lane
    int widx = __builtin_amdgcn_readlane(bi, l);
    const int buf = s&1;
    if (lane==0)
      s_k[buf][wid] = ((unsigned long long)__float_as_uint(wm)<<32) | (uint32_t)(~widx);
    __syncthreads();
    unsigned long long k0=s_k[buf][0], k1=s_k[buf][1], k2=s_k[buf][2], k3=s_k[buf][3];
    unsigned long long ka=(k0>k1)?k0:k1, kb=(k2>k3)?k2:k3;
    unsigned long long kf=(ka>kb)?ka:kb;
    int fi = (int)(~(uint32_t)(kf & 0xffffffffu));
    cx=s_x[fi]; cy=s_y[fi]; cz=s_z[fi];
    if (t==0){
      size_t o2=((size_t)b*NPOINT+s)*3;
      newxyz_f[o2]=cx; newxyz_f[o2+1]=cy; newxyz_f[o2+2]=cz;
      out[o2]=cx; out[o2+1]=cy; out[o2+2]=cz;
    }
    // no 2nd barrier: next iter writes the OTHER slot buffer; reaching that
    // write requires passing this barrier, which all waves' reads precede.
  }
}

// ---------------------------------------------------------------------------
// K2: Ball query (R12).  Coalesced float4 AoS stage; scan reads s_p[3j+c]
// (stride-3 dwords = 2-way bank aliasing, free).  Ballot + prefix-popcount.
// ---------------------------------------------------------------------------
__global__ __launch_bounds__(256) void ballq_kernel(const float* __restrict__ xyz,
                                                    const float* __restrict__ newxyz_f,
                                                    int* __restrict__ ballidx){
  __shared__ float s_p[NPTS*3];       // 48 KB AoS
  __shared__ int s_list[4][NSAMPLE];
  const int b  = blockIdx.x >> 8;     // 256 s-groups per batch
  const int sg = blockIdx.x & 255;
  const int t = threadIdx.x;
  const float* Xb = xyz + (size_t)b*NPTS*3;
  {
    const float4* X4 = (const float4*)Xb;
    float4* S4 = (float4*)s_p;
    #pragma unroll
    for (int i=0;i<12;++i) S4[t + i*256] = X4[t + i*256];   // 3072 float4
  }
  __syncthreads();
  const int lane = t&63, wid = t>>6;
  const int s = sg*4 + wid;
  size_t co = ((size_t)b*NPOINT+s)*3;
  const float cx=newxyz_f[co], cy=newxyz_f[co+1], cz=newxyz_f[co+2];
  const float R2 = 0.04f;             // f32(0.2**2), NEP-50 weak-scalar promotion
  int count = 0;
  for (int j0=0; j0<NPTS && count<NSAMPLE; j0+=64){
    int j=j0+lane;
    float dx=__fsub_rn(cx,s_p[3*j]), dy=__fsub_rn(cy,s_p[3*j+1]), dz=__fsub_rn(cz,s_p[3*j+2]);
    float sq=__fadd_rn(__fadd_rn(__fmul_rn(dx,dx),__fmul_rn(dy,dy)),__fmul_rn(dz,dz));
    bool in = !(sq > R2);
    unsigned long long m = __ballot(in);
    int before = __popcll(m & ((1ull<<lane)-1ull));
    int pos = count + before;
    if (in && pos < NSAMPLE) s_list[wid][pos] = j;
    count += __popcll(m);
  }
  int c = count < NSAMPLE ? count : NSAMPLE;   // >=1: center is in its own ball
  int first = s_list[wid][0];
  if (lane >= c && lane < NSAMPLE) s_list[wid][lane] = first;
  if (lane < NSAMPLE) ballidx[((size_t)b*NPOINT+s)*NSAMPLE + lane] = s_list[wid][lane];
}

// ---------------------------------------------------------------------------
// K3: layer 1 — gather + concat + (67 -> 64) matmul + bias -> h (bf16).
// LDS-staged coalesced gather; 2 threads per row, acc[16].
// ---------------------------------------------------------------------------
#define L1_STRIDE 71
__global__ __launch_bounds__(256,3) void layer1_kernel(const float* __restrict__ xyz,
    const float* __restrict__ points, const int* __restrict__ ballidx,
    const float* __restrict__ newxyz_f, const float* __restrict__ w0,
    const float* __restrict__ b0, unsigned short* __restrict__ h){
  __shared__ float s_w[67*32];            // [c][o_local], c: 0..63=points, 64..66=xyz
  __shared__ float s_b[32];
  __shared__ float s_x[128*L1_STRIDE];    // 128 rows x 71 (67 used)
  __shared__ int   s_j[128];
  const int t = threadIdx.x;
  const int tile = blockIdx.x >> 1;       // 4096 tiles of 128 rows
  const int half = blockIdx.x & 1;        // output channels [half*32, half*32+32)
  const int tileBase = tile*128;
  for (int i=t;i<67*32;i+=256){
    int c=i>>5, oL=i&31;
    int srcc = (c<64) ? (c+3) : (c-64);
    s_w[i] = w0[(half*32+oL)*67 + srcc];
  }
  if (t<32) s_b[t]=b0[half*32+t];
  if (t<128) s_j[t]=ballidx[tileBase+t];
  __syncthreads();
  #pragma unroll
  for (int it=0; it<8; ++it){
    int r = it*16 + (t>>4);
    int row = tileBase + r;
    int bb = row >> 15;                   // 32768 rows per batch
    int j  = s_j[r];
    float4 pv = *(const float4*)(points + ((size_t)bb*NPTS + (size_t)j)*CPTS + (t&15)*4);
    float* xr = s_x + r*L1_STRIDE + (t&15)*4;
    xr[0]=pv.x; xr[1]=pv.y; xr[2]=pv.z; xr[3]=pv.w;
  }
  if (t<128){
    int row = tileBase + t;
    int bs  = row >> 5;
    int bb  = bs >> 10;
    int j   = s_j[t];
    const float* xr = xyz + ((size_t)bb*NPTS + (size_t)j)*3;
    const float* cp = newxyz_f + (size_t)bs*3;
    float* xd = s_x + t*L1_STRIDE + 64;
    xd[0]=(xr[0]-cp[0])/0.2f; xd[1]=(xr[1]-cp[1])/0.2f; xd[2]=(xr[2]-cp[2])/0.2f;
  }
  __syncthreads();
  const int r    = t & 127;
  const int osub = (t>>7)*16;
  const float* xp = s_x + r*L1_STRIDE;
  float acc[16];
  #pragma unroll
  for (int o=0;o<16;++o) acc[o]=0.0f;
  for (int c=0;c<67;++c){
    float xv = xp[c];
    const float4* wr=(const float4*)(s_w + c*32 + osub);
    #pragma unroll
    for (int q=0;q<4;++q){ float4 w=wr[q];
      acc[4*q+0]=fmaf(xv,w.x,acc[4*q+0]); acc[4*q+1]=fmaf(xv,w.y,acc[4*q+1]);
      acc[4*q+2]=fmaf(xv,w.z,acc[4*q+2]); acc[4*q+3]=fmaf(xv,w.w,acc[4*q+3]); }
  }
  uint4* od=(uint4*)(h + (size_t)(tileBase+r)*64 + half*32 + osub);
  #pragma unroll
  for (int q=0;q<2;++q){
    uint4 v;
    v.x=pack2(acc[8*q+0]+s_b[osub+8*q+0], acc[8*q+1]+s_b[osub+8*q+1]);
    v.y=pack2(acc[8*q+2]+s_b[osub+8*q+2], acc[8*q+3]+s_b[osub+8*q+3]);
    v.z=pack2(acc[8*q+4]+s_b[osub+8*q+4], acc[8*q+5]+s_b[osub+8*q+5]);
    v.w=pack2(acc[8*q+6]+s_b[osub+8*q+6], acc[8*q+7]+s_b[osub+8*q+7]);
    od[q]=v;
  }
}

// ---------------------------------------------------------------------------
// Stats over h (bf16, C=64): per-channel sum/sumsq, coalesced uint4 reads,
// LDS block-reduce, one atomicAdd pair per channel per block.
// ---------------------------------------------------------------------------
__global__ __launch_bounds__(256) void stats64_kernel(const unsigned short* __restrict__ h,
                                                      float* __restrict__ st){
  __shared__ float s_red[4][64][8], s_red2[4][64][8];
  const int t=threadIdx.x, lane=t&63, wid=t>>6;
  const int gw = blockIdx.x*4+wid;         // 512 blocks -> 0..2047 waves
  const int rsub = lane>>3;
  float sm[8], sq[8];
  #pragma unroll
  for (int j=0;j<8;++j){ sm[j]=0.f; sq[j]=0.f; }
  for (int it=0; it<32; ++it){
    size_t row = (size_t)gw*256 + it*8 + rsub;
    const uint4* p = (const uint4*)(h + row*64) + (lane&7);
    uint4 v = *p;
    uint32_t ds4[4]={v.x,v.y,v.z,v.w};
    #pragma unroll
    for (int dj=0;dj<4;++dj){
      float a=lo16(ds4[dj]), b2=hi16(ds4[dj]);
      sm[2*dj]+=a;   sq[2*dj]  =fmaf(a,a,sq[2*dj]);
      sm[2*dj+1]+=b2; sq[2*dj+1]=fmaf(b2,b2,sq[2*dj+1]);
    }
  }
  #pragma unroll
  for (int j=0;j<8;++j){ s_red[wid][lane][j]=sm[j]; s_red2[wid][lane][j]=sq[j]; }
  __syncthreads();
  if (t<64){
    float ts=0.f,tq=0.f;
    #pragma unroll
    for (int w=0;w<4;++w)
      #pragma unroll
      for (int m=0;m<8;++m){ int l=(t>>3)+8*m; ts+=s_red[w][l][t&7]; tq+=s_red2[w][l][t&7]; }
    atomicAdd(&st[t*2], ts); atomicAdd(&st[t*2+1], tq);
  }
}

// ---------------------------------------------------------------------------
// K4: layer 2 — (64 -> 64) matmul + bias, in place.  BN(stats0)+ReLU applied
// while staging 128 rows into an LDS tile (stride 65); 2 threads per row,
// acc[32] fully unrolled; no private arrays -> no scratch demotion.
// ---------------------------------------------------------------------------
__global__ __launch_bounds__(256,3) void layer2_kernel(unsigned short* __restrict__ h,
    const float* __restrict__ st, const float* __restrict__ g,
    const float* __restrict__ be, const float* __restrict__ w1,
    const float* __restrict__ b1){
  __shared__ float s_w[64*64];            // 16 KB  [c][o]
  __shared__ float s_x[128*65];           // 33.3 KB
  __shared__ float s_b[64], s_scale[64], s_shift[64];
  const int t=threadIdx.x;
  const int tileBase = blockIdx.x*128;    // 4096 blocks
  for (int i=t;i<64*64;i+=256){ int c=i>>6, o=i&63; s_w[i]=w1[o*64+c]; }
  if (t<64){
    s_b[t]=b1[t];
    float mu=st[t*2]*(1.0f/NROWS);
    float var=st[t*2+1]*(1.0f/NROWS)-mu*mu;
    float inv=1.0f/sqrtf(var+1e-5f);
    s_scale[t]=inv*g[t]; s_shift[t]=be[t]-mu*inv*g[t];
  }
  __syncthreads();
  #pragma unroll
  for (int it=0; it<4; ++it){
    int idx = it*256 + t;
    int r = idx>>3, seg = idx&7;
    uint4 v = *((const uint4*)(h + (size_t)(tileBase+r)*64) + seg);
    float* xd = s_x + r*65 + seg*8;
    uint32_t ds4[4]={v.x,v.y,v.z,v.w};
    #pragma unroll
    for (int dj=0;dj<4;++dj){
      int c = seg*8 + dj*2;
      xd[dj*2+0]=fmaxf(fmaf(lo16(ds4[dj]),s_scale[c],  s_shift[c]),  0.0f);
      xd[dj*2+1]=fmaxf(fmaf(hi16(ds4[dj]),s_scale[c+1],s_shift[c+1]),0.0f);
    }
  }
  __syncthreads();
  const int r    = t & 127;
  const int osub = (t>>7)*32;
  const float* xp = s_x + r*65;
  float acc[32];
  #pragma unroll
  for (int o=0;o<32;++o) acc[o]=0.0f;
  for (int c=0;c<64;++c){
    float xv = xp[c];
    const float4* wr=(const float4*)(s_w + c*64 + osub);
    #pragma unroll
    for (int q=0;q<8;++q){ float4 w=wr[q];
      acc[4*q+0]=fmaf(xv,w.x,acc[4*q+0]); acc[4*q+1]=fmaf(xv,w.y,acc[4*q+1]);
      acc[4*q+2]=fmaf(xv,w.z,acc[4*q+2]); acc[4*q+3]=fmaf(xv,w.w,acc[4*q+3]); }
  }
  uint4* od=(uint4*)(h + (size_t)(tileBase+r)*64 + osub);
  #pragma unroll
  for (int q=0;q<4;++q){
    uint4 v;
    v.x=pack2(acc[8*q+0]+s_b[osub+8*q+0], acc[8*q+1]+s_b[osub+8*q+1]);
    v.y=pack2(acc[8*q+2]+s_b[osub+8*q+2], acc[8*q+3]+s_b[osub+8*q+3]);
    v.z=pack2(acc[8*q+4]+s_b[osub+8*q+4], acc[8*q+5]+s_b[osub+8*q+5]);
    v.w=pack2(acc[8*q+6]+s_b[osub+8*q+6], acc[8*q+7]+s_b[osub+8*q+7]);
    od[q]=v;
  }
}

// ---------------------------------------------------------------------------
// K5: layer 3 — MFMA REWRITE (R12 post-mortem: ~450-500us of the stable
// ~700us tail is fp32 VALU issue in the layer GEMMs; K=64 matmul belongs on
// matrix cores).  16x16x32_bf16, wave-per-s-group (32 rows, K=64, N=128):
//   - A-frags built inline from global h with BN(stats1)+ReLU fused;
//     layout A[m=lane&15][k=quad*8+j] (m120-verified).
//   - B pre-swizzled once into LDS frag table [kt][nt][quad][n15][j]
//     (lane reads its 8 bf16 as one 16B chunk; 2-way bank aliasing only).
//   - 16 MFMAs per s-group; C/D (col=lane&15, row=quad*4+reg, m89-verified)
//     + bias -> per-wave bf16 tile (stride 136) -> max/min/sum/sq column
//     reduce exactly as before.  mm/part contracts unchanged.
// ---------------------------------------------------------------------------
__global__ __launch_bounds__(256,2) void layer3mm_kernel(const unsigned short* __restrict__ h,
    const float* __restrict__ st, const float* __restrict__ g,
    const float* __restrict__ be, const float* __restrict__ w2,
    const float* __restrict__ b2, float* __restrict__ mm, float* __restrict__ part){
  __shared__ __align__(16) unsigned short s_wB[8192];   // 16 KB frag-layout B
  __shared__ unsigned short s_t[4][32*136+8];           // per-wave bf16 out tile
  __shared__ float s_scale[64], s_shift[64], s_b2[128];
  const int t=threadIdx.x, lane=t&63, wid=t>>6;
  const int quad=lane>>4, n15=lane&15;
  for (int i=t;i<8192;i+=256){
    int j=i&7, nn=(i>>3)&15, qq=(i>>7)&3, nt=(i>>9)&7, kt=(i>>12)&1;
    s_wB[i] = f2bf(w2[(nt*16+nn)*64 + (kt*32+qq*8+j)]);
  }
  if (t<64){
    float mu=st[t*2]*(1.0f/NROWS);
    float var=st[t*2+1]*(1.0f/NROWS)-mu*mu;
    float inv=1.0f/sqrtf(var+1e-5f);
    s_scale[t]=inv*g[t]; s_shift[t]=be[t]-mu*inv*g[t];
  }
  if (t<128) s_b2[t]=b2[t];
  __syncthreads();
  // per-lane BN consts for the 16 k slots this lane feeds (constant indices)
  float sc[16], sh[16];
  #pragma unroll
  for (int j=0;j<8;++j){
    sc[j]   = s_scale[quad*8+j];    sh[j]   = s_shift[quad*8+j];
    sc[8+j] = s_scale[32+quad*8+j]; sh[8+j] = s_shift[32+quad*8+j];
  }
  unsigned short* tile = s_t[wid];
  #pragma unroll 1
  for (int i2=0;i2<2;++i2){
    const int sg = blockIdx.x*8 + wid*2 + i2;       // 2048 blocks -> 16384 sgs
    const int rowBase = sg*32;
    bf16x8 A[2][2];                                 // [rowtile][ktile]
    #pragma unroll
    for (int rt=0;rt<2;++rt){
      const unsigned short* hp = h + (size_t)(rowBase + rt*16 + n15)*64 + quad*8;
      #pragma unroll
      for (int kt=0;kt<2;++kt){
        uint4 v = *(const uint4*)(hp + kt*32);
        uint32_t d4[4]={v.x,v.y,v.z,v.w};
        #pragma unroll
        for (int dj=0;dj<4;++dj){
          float xa=fmaxf(fmaf(lo16(d4[dj]),sc[kt*8+dj*2],  sh[kt*8+dj*2]),  0.0f);
          float xb=fmaxf(fmaf(hi16(d4[dj]),sc[kt*8+dj*2+1],sh[kt*8+dj*2+1]),0.0f);
          A[rt][kt][dj*2]   = (short)f2bf(xa);
          A[rt][kt][dj*2+1] = (short)f2bf(xb);
        }
      }
    }
    #pragma unroll
    for (int nt=0;nt<8;++nt){
      bf16x8 B0 = *(const bf16x8*)&s_wB[((nt*4+quad)*16+n15)*8];       // kt=0
      bf16x8 B1 = *(const bf16x8*)&s_wB[(((8+nt)*4+quad)*16+n15)*8];   // kt=1
      f32x4 a0={0.f,0.f,0.f,0.f}, a1={0.f,0.f,0.f,0.f};
      a0 = __builtin_amdgcn_mfma_f32_16x16x32_bf16(A[0][0],B0,a0,0,0,0);
      a0 = __builtin_amdgcn_mfma_f32_16x16x32_bf16(A[0][1],B1,a0,0,0,0);
      a1 = __builtin_amdgcn_mfma_f32_16x16x32_bf16(A[1][0],B0,a1,0,0,0);
      a1 = __builtin_amdgcn_mfma_f32_16x16x32_bf16(A[1][1],B1,a1,0,0,0);
      float bias = s_b2[nt*16+n15];
      #pragma unroll
      for (int r=0;r<4;++r){
        tile[(quad*4+r)*136    + nt*16+n15] = f2bf(a0[r]+bias);
        tile[(16+quad*4+r)*136 + nt*16+n15] = f2bf(a1[r]+bias);
      }
    }
    // wave-coherent LDS (in-order DS pipe): no barrier needed.
    // column reduce: lane owns cols (lane, lane+64) over 32 rows
    float mxA=-3e38f,mnA=3e38f,sA=0.f,qA=0.f;
    float mxB=-3e38f,mnB=3e38f,sB=0.f,qB=0.f;
    #pragma unroll
    for (int r=0;r<32;++r){
      float va=bf2f(tile[r*136+lane]);
      float vb=bf2f(tile[r*136+lane+64]);
      mxA=fmaxf(mxA,va); mnA=fminf(mnA,va); sA+=va; qA=fmaf(va,va,qA);
      mxB=fmaxf(mxB,vb); mnB=fminf(mnB,vb); sB+=vb; qB=fmaf(vb,vb,qB);
    }
    float* mp = mm + (size_t)sg*256;
    mp[lane]=mxA;     mp[lane+64]=mxB;     // max plane
    mp[128+lane]=mnA; mp[192+lane]=mnB;    // min plane
    part[(size_t)sg*256+lane]=sA;      part[(size_t)sg*256+64+lane]=sB;
    part[(size_t)sg*256+128+lane]=qA;  part[(size_t)sg*256+192+lane]=qB;
  }
}

// ---------------------------------------------------------------------------
// K5b: reduce part[16384][256] -> st2 (interleaved {sum,sumsq} per channel).
// ---------------------------------------------------------------------------
__global__ __launch_bounds__(256) void reduce_kernel(const float* __restrict__ part,
                                                     float* __restrict__ st2){
  const int t=threadIdx.x;
  const int base = blockIdx.x*64;
  float acc=0.f;
  for (int r=0;r<64;++r) acc += part[(size_t)(base+r)*256 + t];
  if (t<128) atomicAdd(&st2[t*2], acc);
  else       atomicAdd(&st2[(t-128)*2+1], acc);
}

// ---------------------------------------------------------------------------
// K6: BN(stats2) on max (or min if scale<0) + ReLU -> new_points (f32).
// ---------------------------------------------------------------------------
__global__ __launch_bounds__(256) void final_kernel(const float* __restrict__ mm,
    const float* __restrict__ st, const float* __restrict__ g,
    const float* __restrict__ be, float* __restrict__ out){
  __shared__ float s_scale[128], s_shift[128];
  const int t=threadIdx.x;
  if (t<128){
    float mu=st[t*2]*(1.0f/NROWS);
    float var=st[t*2+1]*(1.0f/NROWS)-mu*mu;
    float inv=1.0f/sqrtf(var+1e-5f);
    s_scale[t]=inv*g[t]; s_shift[t]=be[t]-mu*inv*g[t];
  }
  __syncthreads();
  const int idx = blockIdx.x*256+t;       // bs*128 + ch
  const int ch = idx & 127, bs = idx >> 7;
  float sc=s_scale[ch];
  float v = (sc>=0.f)? mm[(size_t)bs*256+ch] : mm[(size_t)bs*256+128+ch];
  out[(size_t)NB*NPOINT*3 + idx] = fmaxf(fmaf(v,sc,s_shift[ch]),0.0f);
}

// ---------------------------------------------------------------------------
extern "C" void kernel_launch(void* const* d_in, const int* in_sizes, int n_in,
                              void* d_out, int out_size, void* d_ws, size_t ws_size,
                              hipStream_t stream) {
  const float* xyz    = (const float*)d_in[0];
  const float* points = (const float*)d_in[1];
  const float* w0 = (const float*)d_in[2];
  const float* b0 = (const float*)d_in[3];
  const float* g0 = (const float*)d_in[4];
  const float* be0= (const float*)d_in[5];
  const float* w1 = (const float*)d_in[6];
  const float* b1 = (const float*)d_in[7];
  const float* g1 = (const float*)d_in[8];
  const float* be1= (const float*)d_in[9];
  const float* w2 = (const float*)d_in[10];
  const float* b2 = (const float*)d_in[11];
  const float* g2 = (const float*)d_in[12];
  const float* be2= (const float*)d_in[13];
  float* out = (float*)d_out;             // f32 output per reference dtype
  char* ws = (char*)d_ws;

  // ws layout (100 MiB total):
  //   [0,        196608)    newxyz_f (16,1024,3) f32
  //   [196608,   2293760)   ballidx  (16,1024,32) i32
  //   [2293760,  2296832)   stats: 3 slots x 256 f32 {sum,sumsq interleaved}
  //   [4 MiB,    20 MiB)    mm: (16384, {max,min}, 128) f32
  //   [20 MiB,   84 MiB)    h: (524288, 64) bf16 — h1, then h2 in place
  //   [84 MiB,   100 MiB)   part: (16384, 256) f32 BN3 partial sums
  float* newxyz_f = (float*)(ws);
  int*   ballidx  = (int*)(ws + 196608);
  float* stats    = (float*)(ws + 2293760);
  float* mm       = (float*)(ws + 4194304);
  unsigned short* h = (unsigned short*)(ws + 20971520);
  float* part     = (float*)(ws + 88080384);

  hipMemsetAsync(stats, 0, 3072, stream);
  hipLaunchKernelGGL(fps_kernel,     dim3(NB),    dim3(256), 0, stream, xyz, newxyz_f, out);
  hipLaunchKernelGGL(ballq_kernel,   dim3(4096),  dim3(256), 0, stream, xyz, newxyz_f, ballidx);
  hipLaunchKernelGGL(layer1_kernel,  dim3(8192),  dim3(256), 0, stream,
                     xyz, points, ballidx, newxyz_f, w0, b0, h);
  hipLaunchKernelGGL(stats64_kernel, dim3(512),   dim3(256), 0, stream, h, stats + 0);
  hipLaunchKernelGGL(layer2_kernel,  dim3(4096),  dim3(256), 0, stream,
                     h, stats + 0, g0, be0, w1, b1);
  hipLaunchKernelGGL(stats64_kernel, dim3(512),   dim3(256), 0, stream, h, stats + 256);
  hipLaunchKernelGGL(layer3mm_kernel,dim3(2048),  dim3(256), 0, stream,
                     h, stats + 256, g1, be1, w2, b2, mm, part);
  hipLaunchKernelGGL(reduce_kernel,  dim3(256),   dim3(256), 0, stream, part, stats + 512);
  hipLaunchKernelGGL(final_kernel,   dim3(8192),  dim3(256), 0, stream,
                     mm, stats + 512, g2, be2, out);
}

// Round 14
// 978.188 us; speedup vs baseline: 2.3640x; 1.0991x over previous
//
#include <hip/hip_runtime.h>
#include <stdint.h>

// Problem constants
#define NB      16
#define NPTS    4096
#define CPTS    64
#define NPOINT  1024
#define NSAMPLE 32
#define NROWS   (NB*NPOINT*NSAMPLE)   // 524288 rows of (b,s,k)

// f32 -> bf16 (RNE) and bf16 -> f32 (intermediates only; in/out are f32)
__device__ __forceinline__ unsigned short f2bf(float f){
  uint32_t u = __float_as_uint(f);
  uint32_t r = u + 0x7fffu + ((u>>16)&1u);
  return (unsigned short)(r>>16);
}
__device__ __forceinline__ float bf2f(unsigned short u){ return __uint_as_float(((uint32_t)u)<<16); }
__device__ __forceinline__ float lo16(uint32_t d){ return __uint_as_float(d<<16); }
__device__ __forceinline__ float hi16(uint32_t d){ return __uint_as_float(d & 0xffff0000u); }
__device__ __forceinline__ uint32_t pack2(float a, float b){ return ((uint32_t)f2bf(b)<<16) | (uint32_t)f2bf(a); }

// f32 max over DPP (bound_ctrl=1 -> 0 identity; distances >= 0 so safe)
#define FMAX_DPP(m, CTRL) { \
  float _o = __uint_as_float((uint32_t)__builtin_amdgcn_update_dpp(0, (int)__float_as_uint(m), CTRL, 0xF, 0xF, true)); \
  m = fmaxf(m, _o); }

typedef __attribute__((ext_vector_type(8))) short bf16x8;
typedef __attribute__((ext_vector_type(4))) float f32x4;

// ---------------------------------------------------------------------------
// K1: Farthest point sampling (R12 verified, 599us).  R8 structure + f32-only
// DPP wave max + ballot argmax; packed-u64 4-slot cross-wave tournament.
// Tie-break exact (disjoint ordered lane ranges + strict >).
// ---------------------------------------------------------------------------
__global__ __launch_bounds__(256) void fps_kernel(const float* __restrict__ xyz,
                                                  float* __restrict__ newxyz_f,
                                                  float* __restrict__ out){
  __shared__ float s_x[NPTS], s_y[NPTS], s_z[NPTS];
  __shared__ unsigned long long s_k[2][4];
  const int b = blockIdx.x, t = threadIdx.x;
  const float* Xb = xyz + (size_t)b*NPTS*3;
  float px[16], py[16], pz[16], dd[16];
  #pragma unroll
  for (int i=0;i<16;++i){
    int n = t*16+i;
    float x = Xb[n*3+0], y = Xb[n*3+1], z = Xb[n*3+2];
    px[i]=x; py[i]=y; pz[i]=z; dd[i]=1e10f;
    s_x[n]=x; s_y[n]=y; s_z[n]=z;
  }
  if (t==0){
    size_t o=(size_t)b*NPOINT*3;   // sample 0 is index 0 (scan emits prior carry)
    newxyz_f[o]=px[0]; newxyz_f[o+1]=py[0]; newxyz_f[o+2]=pz[0];
    out[o]=px[0]; out[o+1]=py[0]; out[o+2]=pz[0];
  }
  __syncthreads();
  float cx=s_x[0], cy=s_y[0], cz=s_z[0];
  const int lane = t&63, wid = t>>6;
  for (int s=1;s<NPOINT;++s){
    float bv=-1.0f; int bi=0;
    #pragma unroll
    for (int i=0;i<16;++i){
      float dx=__fsub_rn(px[i],cx), dy=__fsub_rn(py[i],cy), dz=__fsub_rn(pz[i],cz);
      float d=__fadd_rn(__fadd_rn(__fmul_rn(dx,dx),__fmul_rn(dy,dy)),__fmul_rn(dz,dz));
      float nd=fminf(dd[i],d); dd[i]=nd;
      if (nd>bv){ bv=nd; bi=t*16+i; }   // ascending i + strict > => lowest idx on tie
    }
    float m = bv;
    FMAX_DPP(m,0x111)   // row_shr:1
    FMAX_DPP(m,0x112)   // row_shr:2
    FMAX_DPP(m,0x114)   // row_shr:4
    FMAX_DPP(m,0x118)   // row_shr:8
    FMAX_DPP(m,0x142)   // row_bcast:15
    FMAX_DPP(m,0x143)   // row_bcast:31
    float wm = __uint_as_float((uint32_t)__builtin_amdgcn_readlane((int)__float_as_uint(m), 63));
    unsigned long long mask = __ballot(bv==wm);
    int l = (int)__ffsll((unsigned long long)mask) - 1;   // lowest tied lane
    int widx = __builtin_amdgcn_readlane(bi, l);
    const int buf = s&1;
    if (lane==0)
      s_k[buf][wid] = ((unsigned long long)__float_as_uint(wm)<<32) | (uint32_t)(~widx);
    __syncthreads();
    unsigned long long k0=s_k[buf][0], k1=s_k[buf][1], k2=s_k[buf][2], k3=s_k[buf][3];
    unsigned long long ka=(k0>k1)?k0:k1, kb=(k2>k3)?k2:k3;
    unsigned long long kf=(ka>kb)?ka:kb;
    int fi = (int)(~(uint32_t)(kf & 0xffffffffu));
    cx=s_x[fi]; cy=s_y[fi]; cz=s_z[fi];
    if (t==0){
      size_t o2=((size_t)b*NPOINT+s)*3;
      newxyz_f[o2]=cx; newxyz_f[o2+1]=cy; newxyz_f[o2+2]=cz;
      out[o2]=cx; out[o2+1]=cy; out[o2+2]=cz;
    }
    // no 2nd barrier: next iter writes the OTHER slot buffer.
  }
}

// ---------------------------------------------------------------------------
// K2: Ball query (R12).  Coalesced float4 AoS stage; scan reads s_p[3j+c]
// (stride-3 dwords = 2-way bank aliasing, free).  Ballot + prefix-popcount.
// ---------------------------------------------------------------------------
__global__ __launch_bounds__(256) void ballq_kernel(const float* __restrict__ xyz,
                                                    const float* __restrict__ newxyz_f,
                                                    int* __restrict__ ballidx){
  __shared__ float s_p[NPTS*3];       // 48 KB AoS
  __shared__ int s_list[4][NSAMPLE];
  const int b  = blockIdx.x >> 8;     // 256 s-groups per batch
  const int sg = blockIdx.x & 255;
  const int t = threadIdx.x;
  const float* Xb = xyz + (size_t)b*NPTS*3;
  {
    const float4* X4 = (const float4*)Xb;
    float4* S4 = (float4*)s_p;
    #pragma unroll
    for (int i=0;i<12;++i) S4[t + i*256] = X4[t + i*256];   // 3072 float4
  }
  __syncthreads();
  const int lane = t&63, wid = t>>6;
  const int s = sg*4 + wid;
  size_t co = ((size_t)b*NPOINT+s)*3;
  const float cx=newxyz_f[co], cy=newxyz_f[co+1], cz=newxyz_f[co+2];
  const float R2 = 0.04f;             // f32(0.2**2)
  int count = 0;
  for (int j0=0; j0<NPTS && count<NSAMPLE; j0+=64){
    int j=j0+lane;
    float dx=__fsub_rn(cx,s_p[3*j]), dy=__fsub_rn(cy,s_p[3*j+1]), dz=__fsub_rn(cz,s_p[3*j+2]);
    float sq=__fadd_rn(__fadd_rn(__fmul_rn(dx,dx),__fmul_rn(dy,dy)),__fmul_rn(dz,dz));
    bool in = !(sq > R2);
    unsigned long long m = __ballot(in);
    int before = __popcll(m & ((1ull<<lane)-1ull));
    int pos = count + before;
    if (in && pos < NSAMPLE) s_list[wid][pos] = j;
    count += __popcll(m);
  }
  int c = count < NSAMPLE ? count : NSAMPLE;   // >=1: center in its own ball
  int first = s_list[wid][0];
  if (lane >= c && lane < NSAMPLE) s_list[wid][lane] = first;
  if (lane < NSAMPLE) ballidx[((size_t)b*NPOINT+s)*NSAMPLE + lane] = s_list[wid][lane];
}

// ---------------------------------------------------------------------------
// K3: layer 1 — gather + concat + (67 -> 64) matmul + bias -> h (bf16).
// ---------------------------------------------------------------------------
#define L1_STRIDE 71
__global__ __launch_bounds__(256,3) void layer1_kernel(const float* __restrict__ xyz,
    const float* __restrict__ points, const int* __restrict__ ballidx,
    const float* __restrict__ newxyz_f, const float* __restrict__ w0,
    const float* __restrict__ b0, unsigned short* __restrict__ h){
  __shared__ float s_w[67*32];            // [c][o_local], c: 0..63=points, 64..66=xyz
  __shared__ float s_b[32];
  __shared__ float s_x[128*L1_STRIDE];    // 128 rows x 71 (67 used)
  __shared__ int   s_j[128];
  const int t = threadIdx.x;
  const int tile = blockIdx.x >> 1;       // 4096 tiles of 128 rows
  const int half = blockIdx.x & 1;        // output channels [half*32, half*32+32)
  const int tileBase = tile*128;
  for (int i=t;i<67*32;i+=256){
    int c=i>>5, oL=i&31;
    int srcc = (c<64) ? (c+3) : (c-64);
    s_w[i] = w0[(half*32+oL)*67 + srcc];
  }
  if (t<32) s_b[t]=b0[half*32+t];
  if (t<128) s_j[t]=ballidx[tileBase+t];
  __syncthreads();
  #pragma unroll
  for (int it=0; it<8; ++it){
    int r = it*16 + (t>>4);
    int row = tileBase + r;
    int bb = row >> 15;                   // 32768 rows per batch
    int j  = s_j[r];
    float4 pv = *(const float4*)(points + ((size_t)bb*NPTS + (size_t)j)*CPTS + (t&15)*4);
    float* xr = s_x + r*L1_STRIDE + (t&15)*4;
    xr[0]=pv.x; xr[1]=pv.y; xr[2]=pv.z; xr[3]=pv.w;
  }
  if (t<128){
    int row = tileBase + t;
    int bs  = row >> 5;
    int bb  = bs >> 10;
    int j   = s_j[t];
    const float* xr = xyz + ((size_t)bb*NPTS + (size_t)j)*3;
    const float* cp = newxyz_f + (size_t)bs*3;
    float* xd = s_x + t*L1_STRIDE + 64;
    xd[0]=(xr[0]-cp[0])/0.2f; xd[1]=(xr[1]-cp[1])/0.2f; xd[2]=(xr[2]-cp[2])/0.2f;
  }
  __syncthreads();
  const int r    = t & 127;
  const int osub = (t>>7)*16;
  const float* xp = s_x + r*L1_STRIDE;
  float acc[16];
  #pragma unroll
  for (int o=0;o<16;++o) acc[o]=0.0f;
  for (int c=0;c<67;++c){
    float xv = xp[c];
    const float4* wr=(const float4*)(s_w + c*32 + osub);
    #pragma unroll
    for (int q=0;q<4;++q){ float4 w=wr[q];
      acc[4*q+0]=fmaf(xv,w.x,acc[4*q+0]); acc[4*q+1]=fmaf(xv,w.y,acc[4*q+1]);
      acc[4*q+2]=fmaf(xv,w.z,acc[4*q+2]); acc[4*q+3]=fmaf(xv,w.w,acc[4*q+3]); }
  }
  uint4* od=(uint4*)(h + (size_t)(tileBase+r)*64 + half*32 + osub);
  #pragma unroll
  for (int q=0;q<2;++q){
    uint4 v;
    v.x=pack2(acc[8*q+0]+s_b[osub+8*q+0], acc[8*q+1]+s_b[osub+8*q+1]);
    v.y=pack2(acc[8*q+2]+s_b[osub+8*q+2], acc[8*q+3]+s_b[osub+8*q+3]);
    v.z=pack2(acc[8*q+4]+s_b[osub+8*q+4], acc[8*q+5]+s_b[osub+8*q+5]);
    v.w=pack2(acc[8*q+6]+s_b[osub+8*q+6], acc[8*q+7]+s_b[osub+8*q+7]);
    od[q]=v;
  }
}

// ---------------------------------------------------------------------------
// Stats over h (bf16, C=64): per-channel sum/sumsq (used once, after layer1).
// ---------------------------------------------------------------------------
__global__ __launch_bounds__(256) void stats64_kernel(const unsigned short* __restrict__ h,
                                                      float* __restrict__ st){
  __shared__ float s_red[4][64][8], s_red2[4][64][8];
  const int t=threadIdx.x, lane=t&63, wid=t>>6;
  const int gw = blockIdx.x*4+wid;         // 512 blocks -> 0..2047 waves
  const int rsub = lane>>3;
  float sm[8], sq[8];
  #pragma unroll
  for (int j=0;j<8;++j){ sm[j]=0.f; sq[j]=0.f; }
  for (int it=0; it<32; ++it){
    size_t row = (size_t)gw*256 + it*8 + rsub;
    const uint4* p = (const uint4*)(h + row*64) + (lane&7);
    uint4 v = *p;
    uint32_t ds4[4]={v.x,v.y,v.z,v.w};
    #pragma unroll
    for (int dj=0;dj<4;++dj){
      float a=lo16(ds4[dj]), b2=hi16(ds4[dj]);
      sm[2*dj]+=a;   sq[2*dj]  =fmaf(a,a,sq[2*dj]);
      sm[2*dj+1]+=b2; sq[2*dj+1]=fmaf(b2,b2,sq[2*dj+1]);
    }
  }
  #pragma unroll
  for (int j=0;j<8;++j){ s_red[wid][lane][j]=sm[j]; s_red2[wid][lane][j]=sq[j]; }
  __syncthreads();
  if (t<64){
    float ts=0.f,tq=0.f;
    #pragma unroll
    for (int w=0;w<4;++w)
      #pragma unroll
      for (int m=0;m<8;++m){ int l=(t>>3)+8*m; ts+=s_red[w][l][t&7]; tq+=s_red2[w][l][t&7]; }
    atomicAdd(&st[t*2], ts); atomicAdd(&st[t*2+1], tq);
  }
}

// ---------------------------------------------------------------------------
// K4: layer 2 — MFMA (R13 post-mortem: MFMA layer3 verified the frag
// machinery; layer2 is the same shape with N=64).  Wave-per-32-row s-group:
// A-frags from h with BN(stats0)+ReLU fused (A[m=lane&15][k=quad*8+j]);
// w1 pre-swizzled to an 8KB LDS frag table; 16 MFMAs/s-group; epilogue +b1
// -> per-wave bf16 tile (stride 72) -> coalesced uint4 IN-PLACE write-back
// (wave reads all its rows before writing) + FUSED stats of the output
// (column sum/sq -> part2, replacing the second 64MB stats pass).
// ---------------------------------------------------------------------------
__global__ __launch_bounds__(256,2) void layer2mm_kernel(unsigned short* __restrict__ h,
    const float* __restrict__ st, const float* __restrict__ g,
    const float* __restrict__ be, const float* __restrict__ w1,
    const float* __restrict__ b1, float* __restrict__ part2){
  __shared__ __align__(16) unsigned short s_wB[4096];   // 8 KB frag-layout B
  __shared__ __align__(16) unsigned short s_t[4][32*72+8];
  __shared__ float s_scale[64], s_shift[64], s_b[64];
  const int t=threadIdx.x, lane=t&63, wid=t>>6;
  const int quad=lane>>4, n15=lane&15;
  for (int i=t;i<4096;i+=256){
    int j=i&7, nn=(i>>3)&15, qq=(i>>7)&3, nt=(i>>9)&3, kt=(i>>11)&1;
    s_wB[i] = f2bf(w1[(nt*16+nn)*64 + (kt*32+qq*8+j)]);
  }
  if (t<64){
    float mu=st[t*2]*(1.0f/NROWS);
    float var=st[t*2+1]*(1.0f/NROWS)-mu*mu;
    float inv=1.0f/sqrtf(var+1e-5f);
    s_scale[t]=inv*g[t]; s_shift[t]=be[t]-mu*inv*g[t];
    s_b[t]=b1[t];
  }
  __syncthreads();
  float sc[16], sh[16];
  #pragma unroll
  for (int j=0;j<8;++j){
    sc[j]   = s_scale[quad*8+j];    sh[j]   = s_shift[quad*8+j];
    sc[8+j] = s_scale[32+quad*8+j]; sh[8+j] = s_shift[32+quad*8+j];
  }
  unsigned short* tile = s_t[wid];
  #pragma unroll 1
  for (int i2=0;i2<2;++i2){
    const int sg = blockIdx.x*8 + wid*2 + i2;       // 2048 blocks -> 16384 sgs
    const int rowBase = sg*32;
    bf16x8 A[2][2];                                 // [rowtile][ktile]
    #pragma unroll
    for (int rt=0;rt<2;++rt){
      const unsigned short* hp = h + (size_t)(rowBase + rt*16 + n15)*64 + quad*8;
      #pragma unroll
      for (int kt=0;kt<2;++kt){
        uint4 v = *(const uint4*)(hp + kt*32);
        uint32_t d4[4]={v.x,v.y,v.z,v.w};
        #pragma unroll
        for (int dj=0;dj<4;++dj){
          float xa=fmaxf(fmaf(lo16(d4[dj]),sc[kt*8+dj*2],  sh[kt*8+dj*2]),  0.0f);
          float xb=fmaxf(fmaf(hi16(d4[dj]),sc[kt*8+dj*2+1],sh[kt*8+dj*2+1]),0.0f);
          A[rt][kt][dj*2]   = (short)f2bf(xa);
          A[rt][kt][dj*2+1] = (short)f2bf(xb);
        }
      }
    }
    #pragma unroll
    for (int nt=0;nt<4;++nt){
      bf16x8 B0 = *(const bf16x8*)&s_wB[(((0*4+nt)*4+quad)*16+n15)*8];   // kt=0
      bf16x8 B1 = *(const bf16x8*)&s_wB[(((1*4+nt)*4+quad)*16+n15)*8];   // kt=1
      f32x4 a0={0.f,0.f,0.f,0.f}, a1={0.f,0.f,0.f,0.f};
      a0 = __builtin_amdgcn_mfma_f32_16x16x32_bf16(A[0][0],B0,a0,0,0,0);
      a0 = __builtin_amdgcn_mfma_f32_16x16x32_bf16(A[0][1],B1,a0,0,0,0);
      a1 = __builtin_amdgcn_mfma_f32_16x16x32_bf16(A[1][0],B0,a1,0,0,0);
      a1 = __builtin_amdgcn_mfma_f32_16x16x32_bf16(A[1][1],B1,a1,0,0,0);
      float bias = s_b[nt*16+n15];
      #pragma unroll
      for (int r=0;r<4;++r){
        tile[(quad*4+r)*72    + nt*16+n15] = f2bf(a0[r]+bias);
        tile[(16+quad*4+r)*72 + nt*16+n15] = f2bf(a1[r]+bias);
      }
    }
    // wave-coherent LDS (in-order DS pipe): no barrier needed.
    // fused stats: lane owns column `lane` over 32 rows
    float sA=0.f,qA=0.f;
    #pragma unroll
    for (int r=0;r<32;++r){
      float v=bf2f(tile[r*72+lane]);
      sA+=v; qA=fmaf(v,v,qA);
    }
    part2[(size_t)sg*128+lane]    = sA;
    part2[(size_t)sg*128+64+lane] = qA;
    // coalesced in-place write-back: 256 tasks (row, 16B-chunk), 4 per lane
    #pragma unroll
    for (int tk=0;tk<4;++tk){
      int task = tk*64 + lane;
      int row = task>>3, q = task&7;
      uint4 v = *(const uint4*)&tile[row*72 + q*8];
      *(uint4*)(h + (size_t)(rowBase+row)*64 + q*8) = v;
    }
  }
}

// ---------------------------------------------------------------------------
// K4b: reduce part2[16384][128] ({sum64,sq64}) -> st (interleaved).
// ---------------------------------------------------------------------------
__global__ __launch_bounds__(128) void reduce64_kernel(const float* __restrict__ part2,
                                                       float* __restrict__ st){
  const int t=threadIdx.x;
  const int base = blockIdx.x*128;        // 128 blocks x 128 rows
  float acc=0.f;
  for (int r=0;r<128;++r) acc += part2[(size_t)(base+r)*128 + t];
  if (t<64) atomicAdd(&st[t*2], acc);
  else      atomicAdd(&st[(t-64)*2+1], acc);
}

// ---------------------------------------------------------------------------
// K5: layer 3 — MFMA (R13 verified).  16x16x32_bf16, wave-per-s-group:
// A-frags inline with BN(stats1)+ReLU; B frag table in LDS; 16 MFMAs;
// C/D + bias -> bf16 tile -> max/min/sum/sq column reduce -> mm/part.
// ---------------------------------------------------------------------------
__global__ __launch_bounds__(256,2) void layer3mm_kernel(const unsigned short* __restrict__ h,
    const float* __restrict__ st, const float* __restrict__ g,
    const float* __restrict__ be, const float* __restrict__ w2,
    const float* __restrict__ b2, float* __restrict__ mm, float* __restrict__ part){
  __shared__ __align__(16) unsigned short s_wB[8192];   // 16 KB frag-layout B
  __shared__ unsigned short s_t[4][32*136+8];           // per-wave bf16 out tile
  __shared__ float s_scale[64], s_shift[64], s_b2[128];
  const int t=threadIdx.x, lane=t&63, wid=t>>6;
  const int quad=lane>>4, n15=lane&15;
  for (int i=t;i<8192;i+=256){
    int j=i&7, nn=(i>>3)&15, qq=(i>>7)&3, nt=(i>>9)&7, kt=(i>>12)&1;
    s_wB[i] = f2bf(w2[(nt*16+nn)*64 + (kt*32+qq*8+j)]);
  }
  if (t<64){
    float mu=st[t*2]*(1.0f/NROWS);
    float var=st[t*2+1]*(1.0f/NROWS)-mu*mu;
    float inv=1.0f/sqrtf(var+1e-5f);
    s_scale[t]=inv*g[t]; s_shift[t]=be[t]-mu*inv*g[t];
  }
  if (t<128) s_b2[t]=b2[t];
  __syncthreads();
  float sc[16], sh[16];
  #pragma unroll
  for (int j=0;j<8;++j){
    sc[j]   = s_scale[quad*8+j];    sh[j]   = s_shift[quad*8+j];
    sc[8+j] = s_scale[32+quad*8+j]; sh[8+j] = s_shift[32+quad*8+j];
  }
  unsigned short* tile = s_t[wid];
  #pragma unroll 1
  for (int i2=0;i2<2;++i2){
    const int sg = blockIdx.x*8 + wid*2 + i2;       // 2048 blocks -> 16384 sgs
    const int rowBase = sg*32;
    bf16x8 A[2][2];                                 // [rowtile][ktile]
    #pragma unroll
    for (int rt=0;rt<2;++rt){
      const unsigned short* hp = h + (size_t)(rowBase + rt*16 + n15)*64 + quad*8;
      #pragma unroll
      for (int kt=0;kt<2;++kt){
        uint4 v = *(const uint4*)(hp + kt*32);
        uint32_t d4[4]={v.x,v.y,v.z,v.w};
        #pragma unroll
        for (int dj=0;dj<4;++dj){
          float xa=fmaxf(fmaf(lo16(d4[dj]),sc[kt*8+dj*2],  sh[kt*8+dj*2]),  0.0f);
          float xb=fmaxf(fmaf(hi16(d4[dj]),sc[kt*8+dj*2+1],sh[kt*8+dj*2+1]),0.0f);
          A[rt][kt][dj*2]   = (short)f2bf(xa);
          A[rt][kt][dj*2+1] = (short)f2bf(xb);
        }
      }
    }
    #pragma unroll
    for (int nt=0;nt<8;++nt){
      bf16x8 B0 = *(const bf16x8*)&s_wB[((nt*4+quad)*16+n15)*8];       // kt=0
      bf16x8 B1 = *(const bf16x8*)&s_wB[(((8+nt)*4+quad)*16+n15)*8];   // kt=1
      f32x4 a0={0.f,0.f,0.f,0.f}, a1={0.f,0.f,0.f,0.f};
      a0 = __builtin_amdgcn_mfma_f32_16x16x32_bf16(A[0][0],B0,a0,0,0,0);
      a0 = __builtin_amdgcn_mfma_f32_16x16x32_bf16(A[0][1],B1,a0,0,0,0);
      a1 = __builtin_amdgcn_mfma_f32_16x16x32_bf16(A[1][0],B0,a1,0,0,0);
      a1 = __builtin_amdgcn_mfma_f32_16x16x32_bf16(A[1][1],B1,a1,0,0,0);
      float bias = s_b2[nt*16+n15];
      #pragma unroll
      for (int r=0;r<4;++r){
        tile[(quad*4+r)*136    + nt*16+n15] = f2bf(a0[r]+bias);
        tile[(16+quad*4+r)*136 + nt*16+n15] = f2bf(a1[r]+bias);
      }
    }
    // wave-coherent LDS: column reduce, lane owns cols (lane, lane+64)
    float mxA=-3e38f,mnA=3e38f,sA=0.f,qA=0.f;
    float mxB=-3e38f,mnB=3e38f,sB=0.f,qB=0.f;
    #pragma unroll
    for (int r=0;r<32;++r){
      float va=bf2f(tile[r*136+lane]);
      float vb=bf2f(tile[r*136+lane+64]);
      mxA=fmaxf(mxA,va); mnA=fminf(mnA,va); sA+=va; qA=fmaf(va,va,qA);
      mxB=fmaxf(mxB,vb); mnB=fminf(mnB,vb); sB+=vb; qB=fmaf(vb,vb,qB);
    }
    float* mp = mm + (size_t)sg*256;
    mp[lane]=mxA;     mp[lane+64]=mxB;     // max plane
    mp[128+lane]=mnA; mp[192+lane]=mnB;    // min plane
    part[(size_t)sg*256+lane]=sA;      part[(size_t)sg*256+64+lane]=sB;
    part[(size_t)sg*256+128+lane]=qA;  part[(size_t)sg*256+192+lane]=qB;
  }
}

// ---------------------------------------------------------------------------
// K5b: reduce part[16384][256] -> st2 (interleaved {sum,sumsq} per channel).
// ---------------------------------------------------------------------------
__global__ __launch_bounds__(256) void reduce_kernel(const float* __restrict__ part,
                                                     float* __restrict__ st2){
  const int t=threadIdx.x;
  const int base = blockIdx.x*64;
  float acc=0.f;
  for (int r=0;r<64;++r) acc += part[(size_t)(base+r)*256 + t];
  if (t<128) atomicAdd(&st2[t*2], acc);
  else       atomicAdd(&st2[(t-128)*2+1], acc);
}

// ---------------------------------------------------------------------------
// K6: BN(stats2) on max (or min if scale<0) + ReLU -> new_points (f32).
// ---------------------------------------------------------------------------
__global__ __launch_bounds__(256) void final_kernel(const float* __restrict__ mm,
    const float* __restrict__ st, const float* __restrict__ g,
    const float* __restrict__ be, float* __restrict__ out){
  __shared__ float s_scale[128], s_shift[128];
  const int t=threadIdx.x;
  if (t<128){
    float mu=st[t*2]*(1.0f/NROWS);
    float var=st[t*2+1]*(1.0f/NROWS)-mu*mu;
    float inv=1.0f/sqrtf(var+1e-5f);
    s_scale[t]=inv*g[t]; s_shift[t]=be[t]-mu*inv*g[t];
  }
  __syncthreads();
  const int idx = blockIdx.x*256+t;       // bs*128 + ch
  const int ch = idx & 127, bs = idx >> 7;
  float sc=s_scale[ch];
  float v = (sc>=0.f)? mm[(size_t)bs*256+ch] : mm[(size_t)bs*256+128+ch];
  out[(size_t)NB*NPOINT*3 + idx] = fmaxf(fmaf(v,sc,s_shift[ch]),0.0f);
}

// ---------------------------------------------------------------------------
extern "C" void kernel_launch(void* const* d_in, const int* in_sizes, int n_in,
                              void* d_out, int out_size, void* d_ws, size_t ws_size,
                              hipStream_t stream) {
  const float* xyz    = (const float*)d_in[0];
  const float* points = (const float*)d_in[1];
  const float* w0 = (const float*)d_in[2];
  const float* b0 = (const float*)d_in[3];
  const float* g0 = (const float*)d_in[4];
  const float* be0= (const float*)d_in[5];
  const float* w1 = (const float*)d_in[6];
  const float* b1 = (const float*)d_in[7];
  const float* g1 = (const float*)d_in[8];
  const float* be1= (const float*)d_in[9];
  const float* w2 = (const float*)d_in[10];
  const float* b2 = (const float*)d_in[11];
  const float* g2 = (const float*)d_in[12];
  const float* be2= (const float*)d_in[13];
  float* out = (float*)d_out;             // f32 output per reference dtype
  char* ws = (char*)d_ws;

  // ws layout (100 MiB total):
  //   [0,        196608)    newxyz_f (16,1024,3) f32
  //   [196608,   2293760)   ballidx  (16,1024,32) i32
  //   [2293760,  2296832)   stats: 3 slots x 256 f32 {sum,sumsq interleaved}
  //   [4 MiB,    20 MiB)    mm: (16384, {max,min}, 128) f32
  //   [20 MiB,   84 MiB)    h: (524288, 64) bf16 — h1, then h2 in place
  //   [84 MiB,   100 MiB)   part: layer2 partials (8MB, consumed by reduce64
  //                         BEFORE layer3mm reuses the region for its own)
  float* newxyz_f = (float*)(ws);
  int*   ballidx  = (int*)(ws + 196608);
  float* stats    = (float*)(ws + 2293760);
  float* mm       = (float*)(ws + 4194304);
  unsigned short* h = (unsigned short*)(ws + 20971520);
  float* part     = (float*)(ws + 88080384);

  hipMemsetAsync(stats, 0, 3072, stream);
  hipLaunchKernelGGL(fps_kernel,     dim3(NB),    dim3(256), 0, stream, xyz, newxyz_f, out);
  hipLaunchKernelGGL(ballq_kernel,   dim3(4096),  dim3(256), 0, stream, xyz, newxyz_f, ballidx);
  hipLaunchKernelGGL(layer1_kernel,  dim3(8192),  dim3(256), 0, stream,
                     xyz, points, ballidx, newxyz_f, w0, b0, h);
  hipLaunchKernelGGL(stats64_kernel, dim3(512),   dim3(256), 0, stream, h, stats + 0);
  hipLaunchKernelGGL(layer2mm_kernel,dim3(2048),  dim3(256), 0, stream,
                     h, stats + 0, g0, be0, w1, b1, part);
  hipLaunchKernelGGL(reduce64_kernel,dim3(128),   dim3(128), 0, stream, part, stats + 256);
  hipLaunchKernelGGL(layer3mm_kernel,dim3(2048),  dim3(256), 0, stream,
                     h, stats + 256, g1, be1, w2, b2, mm, part);
  hipLaunchKernelGGL(reduce_kernel,  dim3(256),   dim3(256), 0, stream, part, stats + 512);
  hipLaunchKernelGGL(final_kernel,   dim3(8192),  dim3(256), 0, stream,
                     mm, stats + 512, g2, be2, out);
}